// Round 13
// baseline (1411.279 us; speedup 1.0000x reference)
//
#include <hip/hip_runtime.h>
#include <hip/hip_bf16.h>
#include <math.h>

#define NH   12
#define HD   64
#define HDIM 768
#define SEQ  257
#define MIDP 128
#define BTOT 2048

typedef __attribute__((ext_vector_type(8))) short short8;
typedef __attribute__((ext_vector_type(4))) float f32x4;

__device__ inline unsigned short f2bf(float x){
  union { float f; unsigned u; } v; v.f = x;
  unsigned r = v.u + 0x7FFFu + ((v.u >> 16) & 1u);
  return (unsigned short)(r >> 16);
}
__device__ inline float bf2f(unsigned short h){
  union { unsigned u; float f; } v; v.u = ((unsigned)h) << 16; return v.f;
}
__device__ inline unsigned cvt2(float lo, float hi){
  union { __hip_bfloat162 h; unsigned u; } z;
  z.h = __float22bfloat162_rn(make_float2(lo, hi));   // lo -> low 16 bits
  return z.u;
}
__device__ inline float dot4(float4 a, float4 b){
  return fmaf(a.x,b.x, fmaf(a.y,b.y, fmaf(a.z,b.z, a.w*b.w)));
}
// LDS-only barrier: drain LDS ops, leave global loads in flight
__device__ inline void barrier_lds(){
  __builtin_amdgcn_sched_barrier(0);
  asm volatile("s_waitcnt lgkmcnt(0)" ::: "memory");
  __builtin_amdgcn_s_barrier();
  __builtin_amdgcn_sched_barrier(0);
}

// ---------------- K0: moments + pe rank-3 decomposition tables ----------------
__global__ __launch_bounds__(256) void k0_pre(
    const float* __restrict__ pe_w, const float* __restrict__ pe_b,
    const float* __restrict__ ln_g, const float* __restrict__ ln_b,
    const float* __restrict__ pos_bias,
    float* __restrict__ pemid, float* __restrict__ alpha, float* __restrict__ beta,
    float* __restrict__ Av, float* __restrict__ Bv, float* __restrict__ Cv,
    float* __restrict__ pbT) {
  __shared__ float red[5][256];
  const int t = threadIdx.x;
  float sw=0.f, sb=0.f, sww=0.f, swb=0.f, sbb=0.f;
  for (int j=t; j<HDIM; j+=256) {
    float w=pe_w[j], b=pe_b[j];
    sw+=w; sb+=b; sww+=w*w; swb+=w*b; sbb+=b*b;
  }
  red[0][t]=sw; red[1][t]=sb; red[2][t]=sww; red[3][t]=swb; red[4][t]=sbb;
  __syncthreads();
  for (int off=128; off>0; off>>=1) {
    if (t<off) {
      red[0][t]+=red[0][t+off]; red[1][t]+=red[1][t+off]; red[2][t]+=red[2][t+off];
      red[3][t]+=red[3][t+off]; red[4][t]+=red[4][t+off];
    }
    __syncthreads();
  }
  const float inv = 1.0f/(float)HDIM;
  const float mw=red[0][0]*inv, mc=red[1][0]*inv;
  const float Vw =red[2][0]*inv - mw*mw;
  const float Cwc=red[3][0]*inv - mw*mc;
  const float Vc =red[4][0]*inv - mc*mc;
  for (int s=t; s<288; s+=256) {
    if (s < SEQ) {
      float pos = (float)(s - MIDP) / ((float)MIDP + 1e-6f);
      float var = pos*pos*Vw + 2.f*pos*Cwc + Vc;
      float rstd = rsqrtf(var + 1e-5f);
      alpha[s] = pos*rstd; beta[s] = rstd;
    } else { alpha[s] = 0.f; beta[s] = 0.f; }
  }
  const float rstd0 = rsqrtf(Vc + 1e-5f);
  for (int j=t; j<HDIM; j+=256) {
    float g = ln_g[j];
    Av[j] = (pe_w[j]-mw)*g;
    Bv[j] = (pe_b[j]-mc)*g;
    Cv[j] = ln_b[j];
    pemid[j] = (pe_b[j]-mc)*rstd0*g + ln_b[j];
  }
  for (int i=t; i<288*16; i+=256) {
    int s = i>>4, h = i&15;
    pbT[i] = (s<SEQ && h<NH) ? pos_bias[h*SEQ+s] : 0.f;
  }
}

// ---------------- tiled fp32 GEMM with epilogue scale ----------------
__global__ __launch_bounds__(256) void gemm64(
    const float* __restrict__ A, long lda, long aoffz,
    const float* __restrict__ Bm, long ldb, long boffz, int bT,
    float* __restrict__ C, long ldc, long coffz,
    int K,
    const float* __restrict__ bias, long biasoffz,
    const float* __restrict__ avec, float scale) {
  __shared__ __align__(16) float As[16][68];
  __shared__ __align__(16) float Bs[16][68];
  const int tid = threadIdx.x;
  const int tx = tid & 15, ty = tid >> 4;
  const int z = blockIdx.z;
  const long n0 = (long)blockIdx.y * 64;
  A  += (long)blockIdx.x*64*lda + (long)z*aoffz;
  Bm += (long)z*boffz;
  C  += (long)blockIdx.x*64*ldc + n0 + (long)z*coffz;
  float acc[4][4] = {};
  const int lm = tid & 63;
  const int lk = tid >> 6;

  for (int k0 = 0; k0 < K; k0 += 16) {
    float4 a = *(const float4*)&A[(long)lm*lda + k0 + lk*4];
    if (avec) {
      float4 av = *(const float4*)&avec[k0 + lk*4];
      a.x += av.x; a.y += av.y; a.z += av.z; a.w += av.w;
    }
    As[lk*4+0][lm]=a.x; As[lk*4+1][lm]=a.y; As[lk*4+2][lm]=a.z; As[lk*4+3][lm]=a.w;
    if (bT) {
      float4 b = *(const float4*)&Bm[(n0+lm)*ldb + k0 + lk*4];
      Bs[lk*4+0][lm]=b.x; Bs[lk*4+1][lm]=b.y; Bs[lk*4+2][lm]=b.z; Bs[lk*4+3][lm]=b.w;
    } else {
      #pragma unroll
      for (int i=0;i<4;i++)
        Bs[lk*4+i][lm] = Bm[(long)(k0+lk*4+i)*ldb + n0 + lm];
    }
    __syncthreads();
    #pragma unroll
    for (int k=0;k<16;k++) {
      float4 a4 = *(const float4*)&As[k][ty*4];
      float4 b4 = *(const float4*)&Bs[k][tx*4];
      float aa[4] = {a4.x,a4.y,a4.z,a4.w};
      float bb[4] = {b4.x,b4.y,b4.z,b4.w};
      #pragma unroll
      for (int i=0;i<4;i++)
        #pragma unroll
        for (int j=0;j<4;j++)
          acc[i][j] = fmaf(aa[i], bb[j], acc[i][j]);
    }
    __syncthreads();
  }
  float4 bs = make_float4(0.f,0.f,0.f,0.f);
  if (bias) bs = *(const float4*)&bias[(long)z*biasoffz + n0 + tx*4];
  #pragma unroll
  for (int i=0;i<4;i++) {
    float4 o;
    o.x = (acc[i][0]+bs.x)*scale; o.y = (acc[i][1]+bs.y)*scale;
    o.z = (acc[i][2]+bs.z)*scale; o.w = (acc[i][3]+bs.w)*scale;
    *(float4*)&C[(long)(ty*4+i)*ldc + tx*4] = o;
  }
}

// ---------------- kp: per-(b,h) scalars ca=u'.A, cb=u'.B, cc=u'.C + q'.bk ----------------
__global__ __launch_bounds__(256) void kp(
    const float* __restrict__ q, const float* __restrict__ u, const float* __restrict__ bk,
    const float* __restrict__ Av, const float* __restrict__ Bv, const float* __restrict__ Cv,
    float* __restrict__ ca, float* __restrict__ cb, float* __restrict__ cc, int nb) {
  const int wid = blockIdx.x*4 + (threadIdx.x >> 6);
  const int lane = threadIdx.x & 63;
  if (wid >= nb*NH) return;
  const int b = wid / NH, h = wid % NH;
  const float* up = u + (long)b*(NH*HDIM) + h*HDIM;
  float pa=0.f, pb_=0.f, pc=0.f;
  #pragma unroll
  for (int e=0;e<3;e++) {
    int c4 = (lane + 64*e)*4;
    float4 uu = *(const float4*)&up[c4];
    pa += dot4(uu, *(const float4*)&Av[c4]);
    pb_+= dot4(uu, *(const float4*)&Bv[c4]);
    pc += dot4(uu, *(const float4*)&Cv[c4]);
  }
  if (lane < 16) {
    float4 qq = *(const float4*)&q[(long)b*HDIM + h*HD + lane*4];
    float4 bb = *(const float4*)&bk[h*HD + lane*4];
    pc += dot4(qq, bb);
  }
  #pragma unroll
  for (int mlog=0; mlog<6; mlog++) {
    int msk = 1<<mlog;
    pa += __shfl_xor(pa, msk);
    pb_+= __shfl_xor(pb_, msk);
    pc += __shfl_xor(pc, msk);
  }
  if (lane == 0) { ca[wid]=pa; cb[wid]=pb_; cc[wid]=pc; }
}

// ---------------- K3 v8b: EXACT round-8 kernel, launch_bounds(256,3) ----------------
// LDS total 54208 B <= 163840/3 -> 3 blocks/CU; register demand ~150 <= 168 budget.
// Everything else identical to the round-8 kernel that measured 736 us total.
__global__ __launch_bounds__(256, 3) void k3_v8(
    const float* __restrict__ hs, int b0,
    const float* __restrict__ u,
    const float* __restrict__ ca, const float* __restrict__ cb, const float* __restrict__ cc,
    const float* __restrict__ alpha, const float* __restrict__ beta,
    const float* __restrict__ Av, const float* __restrict__ Bv, const float* __restrict__ Cv,
    const float* __restrict__ pbT, float* __restrict__ mout) {
  const int t   = threadIdx.x;
  const int l   = t & 63;
  const int w   = t >> 6;
  const int l15 = l & 15;
  const int lg  = l >> 4;
  const int bb  = blockIdx.x;
  const int b   = b0 + bb;

  __shared__ __align__(16) unsigned short xbuf[2*12288];  // x_row[16*768] | colT[768*16]
  unsigned short* xrow = xbuf;
  unsigned short* colT = xbuf + 12288;
  __shared__ float sred[4][16][17];                       // 4.4 KB
  __shared__ __align__(16) unsigned short wlT[16*16];     // [h][s] bf16, 512 B
  __shared__ float hsum[3][16];

  // u' B-frags (score), wave w covers K-quarter [w*192, +192)
  const float* ub = u + (long)bb*(NH*HDIM);
  short8 uf[6];
  #pragma unroll
  for (int kt=0; kt<6; kt++) {
    union { uint4 q; short8 s8; } s; s.q = make_uint4(0,0,0,0);
    if (l15 < NH) {
      const float* p = ub + l15*HDIM + w*192 + kt*32 + lg*8;
      float4 x0 = *(const float4*)p;
      float4 x1 = *(const float4*)(p+4);
      s.q.x = cvt2(x0.x,x0.y); s.q.y = cvt2(x0.z,x0.w);
      s.q.z = cvt2(x1.x,x1.y); s.q.w = cvt2(x1.z,x1.w);
    }
    uf[kt] = s.s8;
  }
  float cah=0.f, cbh=0.f, cch=0.f;
  if (w==0 && l15<NH) { cah=ca[bb*NH+l15]; cbh=cb[bb*NH+l15]; cch=cc[bb*NH+l15]; }

  f32x4 pv[12];
  #pragma unroll
  for (int i=0;i<12;i++){ f32x4 z={0.f,0.f,0.f,0.f}; pv[i]=z; }
  float rs_p=0.f, sa_p=0.f, sb_p=0.f;

  const float* hrow = hs + (long)b*SEQ*HDIM;
  const int rp = t >> 5;          // 0..7: rows rp*2, rp*2+1
  const int cq = t & 31;          // interleaved col-quads: j = cq*4 + e*128 + d
  union { float4 v4[12]; float f[48]; } g;   // [rr*6+e]

  // chunk-0 load + stage
  #pragma unroll
  for (int rr=0; rr<2; ++rr)
    #pragma unroll
    for (int e=0; e<6; ++e)
      g.v4[rr*6+e] = *(const float4*)&hrow[(long)(rp*2+rr)*HDIM + cq*4 + e*128];
  #pragma unroll
  for (int rr=0; rr<2; ++rr) {
    const int srow = rp*2+rr;
    #pragma unroll
    for (int e=0; e<6; ++e) {
      float4 v = g.v4[rr*6+e];
      uint2 pk; pk.x = cvt2(v.x,v.y); pk.y = cvt2(v.z,v.w);
      const int c = cq*4 + e*128;
      *(uint2*)&xrow[srow*768 + (c ^ ((srow&7)<<3))] = pk;
    }
  }
  #pragma unroll
  for (int e=0; e<6; ++e)
    #pragma unroll
    for (int d=0; d<4; ++d) {
      const int j = cq*4 + e*128 + d;
      unsigned v = cvt2(g.f[e*4+d], g.f[24+e*4+d]);
      *(unsigned*)&colT[j*16 + ((rp*2) ^ (((j>>2)&1)<<3))] = v;
    }
  __syncthreads();

  #pragma unroll 1
  for (int c=0; c<17; ++c) {
    // issue next-chunk loads (ride across lgkm barriers)
    if (c < 16) {
      #pragma unroll
      for (int rr=0; rr<2; ++rr) {
        int sg = (c+1)*16 + rp*2 + rr; if (sg > SEQ-1) sg = SEQ-1;
        #pragma unroll
        for (int e=0; e<6; ++e)
          g.v4[rr*6+e] = *(const float4*)&hrow[(long)sg*HDIM + cq*4 + e*128];
      }
    }
    // ---- score MFMA (K-quarter per wave) ----
    {
      f32x4 acc = {0.f,0.f,0.f,0.f};
      #pragma unroll
      for (int kt=0; kt<6; kt++) {
        const int col = w*192 + kt*32 + lg*8;
        uint4 raw = *(const uint4*)&xrow[l15*768 + (col ^ ((l15&7)<<3))];
        union { uint4 q; short8 s8; } A; A.q = raw;
        acc = __builtin_amdgcn_mfma_f32_16x16x32_bf16(A.s8, uf[kt], acc, 0, 0, 0);
      }
      #pragma unroll
      for (int r=0; r<4; ++r) sred[w][lg*4+r][l15] = acc[r];
    }
    barrier_lds();                        // BAR1: sred ready
    // ---- exp on wave 0 only -> wlT ----
    if (w == 0) {
      #pragma unroll
      for (int r=0; r<4; ++r) {
        const int s = lg*4 + r, sg = c*16 + s;
        float S = sred[0][s][l15]+sred[1][s][l15]+sred[2][s][l15]+sred[3][s][l15];
        float al = alpha[sg], be = beta[sg];
        float sc = S + fmaf(cah, al, fmaf(cbh, be, cch)) + pbT[sg*16 + l15];
        float wv = (sg < SEQ && l15 < NH) ? __expf(sc) : 0.f;
        unsigned short wb = f2bf(wv);
        float wr = bf2f(wb);
        rs_p += wr; sa_p = fmaf(wr, al, sa_p); sb_p = fmaf(wr, be, sb_p);
        wlT[l15*16 + s] = wb;
      }
    }
    barrier_lds();                        // BAR2: wlT ready
    // ---- PV MFMA: m^T[j][h] += x^T * w ----
    {
      union { uint4 q; short8 s8; } B; B.q = make_uint4(0,0,0,0);
      if (lg < 2) B.q = *(const uint4*)&wlT[l15*16 + lg*8];
      #pragma unroll
      for (int tau=0; tau<12; ++tau) {
        const int j = w*192 + tau*16 + l15;
        union { uint4 q; short8 s8; } A; A.q = make_uint4(0,0,0,0);
        if (lg < 2) A.q = *(const uint4*)&colT[j*16 + ((lg*8) ^ (((j>>2)&1)<<3))];
        pv[tau] = __builtin_amdgcn_mfma_f32_16x16x32_bf16(A.s8, B.s8, pv[tau], 0, 0, 0);
      }
      // stage next x_row (score(c) done reading since BAR1)
      if (c < 16) {
        #pragma unroll
        for (int rr=0; rr<2; ++rr) {
          const int srow = rp*2+rr;
          #pragma unroll
          for (int e=0; e<6; ++e) {
            float4 v = g.v4[rr*6+e];
            uint2 pk; pk.x = cvt2(v.x,v.y); pk.y = cvt2(v.z,v.w);
            const int cc2 = cq*4 + e*128;
            *(uint2*)&xrow[srow*768 + (cc2 ^ ((srow&7)<<3))] = pk;
          }
        }
      }
    }
    barrier_lds();                        // BAR3: PV done -> colT writable
    if (c < 16) {
      #pragma unroll
      for (int e=0; e<6; ++e)
        #pragma unroll
        for (int d=0; d<4; ++d) {
          const int j = cq*4 + e*128 + d;
          unsigned v = cvt2(g.f[e*4+d], g.f[24+e*4+d]);
          *(unsigned*)&colT[j*16 + ((rp*2) ^ (((j>>2)&1)<<3))] = v;
        }
    }
    // colT writes drain at next BAR1 (before any PV(c+1) read) — safe.
  }

  // ---- softmax sums (wave 0 holds partials over s = lg*4+r) ----
  if (w == 0) {
    rs_p += __shfl_xor(rs_p,16); rs_p += __shfl_xor(rs_p,32);
    sa_p += __shfl_xor(sa_p,16); sa_p += __shfl_xor(sa_p,32);
    sb_p += __shfl_xor(sb_p,16); sb_p += __shfl_xor(sb_p,32);
    if (l < 16) { hsum[0][l15]=rs_p; hsum[1][l15]=sa_p; hsum[2][l15]=sb_p; }
  }
  __syncthreads();

  // ---- m^T regs -> LDS (overlay xbuf), then coalesced epilogue ----
  float* mlds = (float*)xbuf;             // [12][772]
  if (l15 < NH) {
    #pragma unroll
    for (int tau=0; tau<12; ++tau)
      #pragma unroll
      for (int r=0; r<4; ++r) {
        const int j = w*192 + tau*16 + lg*4 + r;
        mlds[l15*772 + j] = pv[tau][r];
      }
  }
  __syncthreads();
  float* mo = mout + (long)bb*(NH*HDIM);
  #pragma unroll
  for (int e=0; e<9; ++e) {
    const int idx = t + 256*e;            // 0..2303
    const int h = idx/192, c4 = (idx%192)*4;
    const float invr = 1.0f/hsum[0][h];
    const float fa = hsum[1][h]*invr, fb = hsum[2][h]*invr;
    float4 mv = *(const float4*)&mlds[h*772 + c4];
    float4 av = *(const float4*)&Av[c4];
    float4 bv4 = *(const float4*)&Bv[c4];
    float4 cv4 = *(const float4*)&Cv[c4];
    float4 o;
    o.x = fmaf(mv.x, invr, fmaf(fa, av.x, fmaf(fb, bv4.x, cv4.x)));
    o.y = fmaf(mv.y, invr, fmaf(fa, av.y, fmaf(fb, bv4.y, cv4.y)));
    o.z = fmaf(mv.z, invr, fmaf(fa, av.z, fmaf(fb, bv4.z, cv4.z)));
    o.w = fmaf(mv.w, invr, fmaf(fa, av.w, fmaf(fb, bv4.w, cv4.w)));
    *(float4*)&mo[h*HDIM + c4] = o;
  }
}

extern "C" void kernel_launch(void* const* d_in, const int* in_sizes, int n_in,
                              void* d_out, int out_size, void* d_ws, size_t ws_size,
                              hipStream_t stream) {
  (void)in_sizes; (void)n_in; (void)out_size;
  const float* hs   = (const float*)d_in[0];
  const float* Wq   = (const float*)d_in[1];
  const float* bq   = (const float*)d_in[2];
  const float* Wk   = (const float*)d_in[3];
  const float* bk   = (const float*)d_in[4];
  const float* Wv   = (const float*)d_in[5];
  const float* bv   = (const float*)d_in[6];
  const float* Wo   = (const float*)d_in[7];
  const float* bo   = (const float*)d_in[8];
  const float* pe_w = (const float*)d_in[9];
  const float* pe_b = (const float*)d_in[10];
  const float* ln_g = (const float*)d_in[11];
  const float* ln_b = (const float*)d_in[12];
  const float* pos_bias = (const float*)d_in[13];
  float* out = (float*)d_out;

  float* wsf   = (float*)d_ws;
  float* pemid = wsf;               // 768
  float* alpha = pemid + 768;       // 288
  float* beta  = alpha + 288;       // 288
  float* Avec  = beta  + 288;       // 768
  float* Bvec  = Avec  + 768;       // 768
  float* Cvec  = Bvec  + 768;       // 768
  float* pbT   = Cvec  + 768;       // 288*16 = 4608
  float* base  = pbT   + 4608;      // fixed total = 8256 floats

  const long perB = 768L + 36L + 9216L + 9216L + 768L;   // q + (ca,cb,cc) + u + m + ctx
  long availF = (long)(ws_size/4) - 8256;
  long chunkB = (availF > 0) ? (availF / perB) : 0;
  if (chunkB > BTOT) chunkB = BTOT;
  chunkB &= ~63L;
  if (chunkB < 64) chunkB = 64;

  float* qb   = base;
  float* cab  = qb  + chunkB*HDIM;
  float* cbb  = cab + chunkB*NH;
  float* ccb  = cbb + chunkB*NH;
  float* ub   = ccb + chunkB*NH;
  float* mb   = ub  + chunkB*(long)NH*HDIM;
  float* ctxb = mb  + chunkB*(long)NH*HDIM;

  k0_pre<<<dim3(1), dim3(256), 0, stream>>>(pe_w, pe_b, ln_g, ln_b, pos_bias,
                                            pemid, alpha, beta, Avec, Bvec, Cvec, pbT);

  for (long b0 = 0; b0 < BTOT; b0 += chunkB) {
    long cbN = (BTOT - b0 < chunkB) ? (BTOT - b0) : chunkB;
    int mt = (int)(cbN/64);
    // K1: q' = 0.125*((hs[:,mid,:] + pe_mid) @ Wq^T + bq)
    gemm64<<<dim3(mt,12,1), dim3(256), 0, stream>>>(
        hs + b0*(long)SEQ*HDIM + (long)MIDP*HDIM, (long)SEQ*HDIM, 0L,
        Wq, (long)HDIM, 0L, 1,
        qb, (long)HDIM, 0L,
        HDIM, bq, 0L, pemid, 0.125f);
    // K2: u'[b,h,:] = q'[b,h,:] @ Wk_h
    gemm64<<<dim3(mt,12,12), dim3(256), 0, stream>>>(
        qb, (long)HDIM, (long)HD,
        Wk, (long)HDIM, (long)HD*HDIM, 0,
        ub, (long)NH*HDIM, (long)HDIM,
        HD, (const float*)nullptr, 0L, (const float*)nullptr, 1.0f);
    // kp: per-(b,h) pe/bias dot scalars
    int nw = (int)(cbN*NH);
    kp<<<dim3((nw+3)/4), dim3(256), 0, stream>>>(qb, ub, bk, Avec, Bvec, Cvec,
                                                 cab, cbb, ccb, (int)cbN);
    // K3: fused MFMA scores + softmax-weighted mean
    k3_v8<<<dim3((int)cbN), dim3(256), 0, stream>>>(
        hs, (int)b0, ub, cab, cbb, ccb, alpha, beta, Avec, Bvec, Cvec, pbT, mb);
    // K4: ctx = Wv_h @ m + bv
    gemm64<<<dim3(mt,1,12), dim3(256), 0, stream>>>(
        mb, (long)NH*HDIM, (long)HDIM,
        Wv, (long)HDIM, (long)HD*HDIM, 1,
        ctxb, (long)HDIM, (long)HD,
        HDIM, bv, (long)HD, (const float*)nullptr, 1.0f);
    // K5: out = ctx @ Wo^T + bo
    gemm64<<<dim3(mt,12,1), dim3(256), 0, stream>>>(
        ctxb, (long)HDIM, 0L,
        Wo, (long)HDIM, 0L, 1,
        out + b0*(long)HDIM, (long)HDIM, 0L,
        HDIM, bo, 0L, (const float*)nullptr, 1.0f);
  }
}

// Round 14
// 736.367 us; speedup vs baseline: 1.9165x; 1.9165x over previous
//
#include <hip/hip_runtime.h>
#include <hip/hip_bf16.h>
#include <math.h>

#define NH   12
#define HD   64
#define HDIM 768
#define SEQ  257
#define MIDP 128
#define BTOT 2048

typedef __attribute__((ext_vector_type(8))) short short8;
typedef __attribute__((ext_vector_type(4))) float f32x4;

__device__ inline unsigned short f2bf(float x){
  union { float f; unsigned u; } v; v.f = x;
  unsigned r = v.u + 0x7FFFu + ((v.u >> 16) & 1u);
  return (unsigned short)(r >> 16);
}
__device__ inline float bf2f(unsigned short h){
  union { unsigned u; float f; } v; v.u = ((unsigned)h) << 16; return v.f;
}
__device__ inline unsigned cvt2(float lo, float hi){
  union { __hip_bfloat162 h; unsigned u; } z;
  z.h = __float22bfloat162_rn(make_float2(lo, hi));   // lo -> low 16 bits
  return z.u;
}
__device__ inline float dot4(float4 a, float4 b){
  return fmaf(a.x,b.x, fmaf(a.y,b.y, fmaf(a.z,b.z, a.w*b.w)));
}
// LDS-only barrier: drain LDS ops, leave global loads in flight
__device__ inline void barrier_lds(){
  __builtin_amdgcn_sched_barrier(0);
  asm volatile("s_waitcnt lgkmcnt(0)" ::: "memory");
  __builtin_amdgcn_s_barrier();
  __builtin_amdgcn_sched_barrier(0);
}

// ---------------- K0: moments + pe rank-3 decomposition tables ----------------
__global__ __launch_bounds__(256) void k0_pre(
    const float* __restrict__ pe_w, const float* __restrict__ pe_b,
    const float* __restrict__ ln_g, const float* __restrict__ ln_b,
    const float* __restrict__ pos_bias,
    float* __restrict__ pemid, float* __restrict__ alpha, float* __restrict__ beta,
    float* __restrict__ Av, float* __restrict__ Bv, float* __restrict__ Cv,
    float* __restrict__ pbT) {
  __shared__ float red[5][256];
  const int t = threadIdx.x;
  float sw=0.f, sb=0.f, sww=0.f, swb=0.f, sbb=0.f;
  for (int j=t; j<HDIM; j+=256) {
    float w=pe_w[j], b=pe_b[j];
    sw+=w; sb+=b; sww+=w*w; swb+=w*b; sbb+=b*b;
  }
  red[0][t]=sw; red[1][t]=sb; red[2][t]=sww; red[3][t]=swb; red[4][t]=sbb;
  __syncthreads();
  for (int off=128; off>0; off>>=1) {
    if (t<off) {
      red[0][t]+=red[0][t+off]; red[1][t]+=red[1][t+off]; red[2][t]+=red[2][t+off];
      red[3][t]+=red[3][t+off]; red[4][t]+=red[4][t+off];
    }
    __syncthreads();
  }
  const float inv = 1.0f/(float)HDIM;
  const float mw=red[0][0]*inv, mc=red[1][0]*inv;
  const float Vw =red[2][0]*inv - mw*mw;
  const float Cwc=red[3][0]*inv - mw*mc;
  const float Vc =red[4][0]*inv - mc*mc;
  for (int s=t; s<288; s+=256) {
    if (s < SEQ) {
      float pos = (float)(s - MIDP) / ((float)MIDP + 1e-6f);
      float var = pos*pos*Vw + 2.f*pos*Cwc + Vc;
      float rstd = rsqrtf(var + 1e-5f);
      alpha[s] = pos*rstd; beta[s] = rstd;
    } else { alpha[s] = 0.f; beta[s] = 0.f; }
  }
  const float rstd0 = rsqrtf(Vc + 1e-5f);
  for (int j=t; j<HDIM; j+=256) {
    float g = ln_g[j];
    Av[j] = (pe_w[j]-mw)*g;
    Bv[j] = (pe_b[j]-mc)*g;
    Cv[j] = ln_b[j];
    pemid[j] = (pe_b[j]-mc)*rstd0*g + ln_b[j];
  }
  for (int i=t; i<288*16; i+=256) {
    int s = i>>4, h = i&15;
    pbT[i] = (s<SEQ && h<NH) ? pos_bias[h*SEQ+s] : 0.f;
  }
}

// ---------------- tiled fp32 GEMM with epilogue scale ----------------
__global__ __launch_bounds__(256) void gemm64(
    const float* __restrict__ A, long lda, long aoffz,
    const float* __restrict__ Bm, long ldb, long boffz, int bT,
    float* __restrict__ C, long ldc, long coffz,
    int K,
    const float* __restrict__ bias, long biasoffz,
    const float* __restrict__ avec, float scale) {
  __shared__ __align__(16) float As[16][68];
  __shared__ __align__(16) float Bs[16][68];
  const int tid = threadIdx.x;
  const int tx = tid & 15, ty = tid >> 4;
  const int z = blockIdx.z;
  const long n0 = (long)blockIdx.y * 64;
  A  += (long)blockIdx.x*64*lda + (long)z*aoffz;
  Bm += (long)z*boffz;
  C  += (long)blockIdx.x*64*ldc + n0 + (long)z*coffz;
  float acc[4][4] = {};
  const int lm = tid & 63;
  const int lk = tid >> 6;

  for (int k0 = 0; k0 < K; k0 += 16) {
    float4 a = *(const float4*)&A[(long)lm*lda + k0 + lk*4];
    if (avec) {
      float4 av = *(const float4*)&avec[k0 + lk*4];
      a.x += av.x; a.y += av.y; a.z += av.z; a.w += av.w;
    }
    As[lk*4+0][lm]=a.x; As[lk*4+1][lm]=a.y; As[lk*4+2][lm]=a.z; As[lk*4+3][lm]=a.w;
    if (bT) {
      float4 b = *(const float4*)&Bm[(n0+lm)*ldb + k0 + lk*4];
      Bs[lk*4+0][lm]=b.x; Bs[lk*4+1][lm]=b.y; Bs[lk*4+2][lm]=b.z; Bs[lk*4+3][lm]=b.w;
    } else {
      #pragma unroll
      for (int i=0;i<4;i++)
        Bs[lk*4+i][lm] = Bm[(long)(k0+lk*4+i)*ldb + n0 + lm];
    }
    __syncthreads();
    #pragma unroll
    for (int k=0;k<16;k++) {
      float4 a4 = *(const float4*)&As[k][ty*4];
      float4 b4 = *(const float4*)&Bs[k][tx*4];
      float aa[4] = {a4.x,a4.y,a4.z,a4.w};
      float bb[4] = {b4.x,b4.y,b4.z,b4.w};
      #pragma unroll
      for (int i=0;i<4;i++)
        #pragma unroll
        for (int j=0;j<4;j++)
          acc[i][j] = fmaf(aa[i], bb[j], acc[i][j]);
    }
    __syncthreads();
  }
  float4 bs = make_float4(0.f,0.f,0.f,0.f);
  if (bias) bs = *(const float4*)&bias[(long)z*biasoffz + n0 + tx*4];
  #pragma unroll
  for (int i=0;i<4;i++) {
    float4 o;
    o.x = (acc[i][0]+bs.x)*scale; o.y = (acc[i][1]+bs.y)*scale;
    o.z = (acc[i][2]+bs.z)*scale; o.w = (acc[i][3]+bs.w)*scale;
    *(float4*)&C[(long)(ty*4+i)*ldc + tx*4] = o;
  }
}

// ---------------- kp: per-(b,h) scalars ca=u'.A, cb=u'.B, cc=u'.C + q'.bk ----------------
__global__ __launch_bounds__(256) void kp(
    const float* __restrict__ q, const float* __restrict__ u, const float* __restrict__ bk,
    const float* __restrict__ Av, const float* __restrict__ Bv, const float* __restrict__ Cv,
    float* __restrict__ ca, float* __restrict__ cb, float* __restrict__ cc, int nb) {
  const int wid = blockIdx.x*4 + (threadIdx.x >> 6);
  const int lane = threadIdx.x & 63;
  if (wid >= nb*NH) return;
  const int b = wid / NH, h = wid % NH;
  const float* up = u + (long)b*(NH*HDIM) + h*HDIM;
  float pa=0.f, pb_=0.f, pc=0.f;
  #pragma unroll
  for (int e=0;e<3;e++) {
    int c4 = (lane + 64*e)*4;
    float4 uu = *(const float4*)&up[c4];
    pa += dot4(uu, *(const float4*)&Av[c4]);
    pb_+= dot4(uu, *(const float4*)&Bv[c4]);
    pc += dot4(uu, *(const float4*)&Cv[c4]);
  }
  if (lane < 16) {
    float4 qq = *(const float4*)&q[(long)b*HDIM + h*HD + lane*4];
    float4 bb = *(const float4*)&bk[h*HD + lane*4];
    pc += dot4(qq, bb);
  }
  #pragma unroll
  for (int mlog=0; mlog<6; mlog++) {
    int msk = 1<<mlog;
    pa += __shfl_xor(pa, msk);
    pb_+= __shfl_xor(pb_, msk);
    pc += __shfl_xor(pc, msk);
  }
  if (lane == 0) { ca[wid]=pa; cb[wid]=pb_; cc[wid]=pc; }
}

// ---------------- K3 v8 (EXACT round-8 kernel, launch_bounds(256,2)) ----------------
// Block per batch, CS=16 chunks. Stager: 2 rows x 24 interleaved cols/thread;
// writes x_row (b64, XOR swizzle (s&7)<<3) and colT[j][s] (s-pairs packed b32,
// XOR ((j>>2)&1)<<3). Score: K-split MFMA (A=x_row rows, B=uf regs) + sred.
// Exp: wave 0 only -> wlT[h][s] bf16. PV: mfma(A=colT rows (lane=j), B=wlT row
// (lane=h)) -> m^T in regs. 3 lgkm-only barriers/chunk; vmcnt never drained.
__global__ __launch_bounds__(256, 2) void k3_v8(
    const float* __restrict__ hs, int b0,
    const float* __restrict__ u,
    const float* __restrict__ ca, const float* __restrict__ cb, const float* __restrict__ cc,
    const float* __restrict__ alpha, const float* __restrict__ beta,
    const float* __restrict__ Av, const float* __restrict__ Bv, const float* __restrict__ Cv,
    const float* __restrict__ pbT, float* __restrict__ mout) {
  const int t   = threadIdx.x;
  const int l   = t & 63;
  const int w   = t >> 6;
  const int l15 = l & 15;
  const int lg  = l >> 4;
  const int bb  = blockIdx.x;
  const int b   = b0 + bb;

  __shared__ __align__(16) unsigned short xbuf[2*12288];  // x_row[16*768] | colT[768*16]
  unsigned short* xrow = xbuf;
  unsigned short* colT = xbuf + 12288;
  __shared__ float sred[4][16][17];                       // 4.4 KB
  __shared__ __align__(16) unsigned short wlT[16*16];     // [h][s] bf16, 512 B
  __shared__ float hsum[3][16];

  // u' B-frags (score), wave w covers K-quarter [w*192, +192)
  const float* ub = u + (long)bb*(NH*HDIM);
  short8 uf[6];
  #pragma unroll
  for (int kt=0; kt<6; kt++) {
    union { uint4 q; short8 s8; } s; s.q = make_uint4(0,0,0,0);
    if (l15 < NH) {
      const float* p = ub + l15*HDIM + w*192 + kt*32 + lg*8;
      float4 x0 = *(const float4*)p;
      float4 x1 = *(const float4*)(p+4);
      s.q.x = cvt2(x0.x,x0.y); s.q.y = cvt2(x0.z,x0.w);
      s.q.z = cvt2(x1.x,x1.y); s.q.w = cvt2(x1.z,x1.w);
    }
    uf[kt] = s.s8;
  }
  float cah=0.f, cbh=0.f, cch=0.f;
  if (w==0 && l15<NH) { cah=ca[bb*NH+l15]; cbh=cb[bb*NH+l15]; cch=cc[bb*NH+l15]; }

  f32x4 pv[12];
  #pragma unroll
  for (int i=0;i<12;i++){ f32x4 z={0.f,0.f,0.f,0.f}; pv[i]=z; }
  float rs_p=0.f, sa_p=0.f, sb_p=0.f;

  const float* hrow = hs + (long)b*SEQ*HDIM;
  const int rp = t >> 5;          // 0..7: rows rp*2, rp*2+1
  const int cq = t & 31;          // interleaved col-quads: j = cq*4 + e*128 + d
  union { float4 v4[12]; float f[48]; } g;   // [rr*6+e]

  // chunk-0 load + stage
  #pragma unroll
  for (int rr=0; rr<2; ++rr)
    #pragma unroll
    for (int e=0; e<6; ++e)
      g.v4[rr*6+e] = *(const float4*)&hrow[(long)(rp*2+rr)*HDIM + cq*4 + e*128];
  #pragma unroll
  for (int rr=0; rr<2; ++rr) {
    const int srow = rp*2+rr;
    #pragma unroll
    for (int e=0; e<6; ++e) {
      float4 v = g.v4[rr*6+e];
      uint2 pk; pk.x = cvt2(v.x,v.y); pk.y = cvt2(v.z,v.w);
      const int c = cq*4 + e*128;
      *(uint2*)&xrow[srow*768 + (c ^ ((srow&7)<<3))] = pk;
    }
  }
  #pragma unroll
  for (int e=0; e<6; ++e)
    #pragma unroll
    for (int d=0; d<4; ++d) {
      const int j = cq*4 + e*128 + d;
      unsigned v = cvt2(g.f[e*4+d], g.f[24+e*4+d]);
      *(unsigned*)&colT[j*16 + ((rp*2) ^ (((j>>2)&1)<<3))] = v;
    }
  __syncthreads();

  #pragma unroll 1
  for (int c=0; c<17; ++c) {
    // issue next-chunk loads (ride across lgkm barriers)
    if (c < 16) {
      #pragma unroll
      for (int rr=0; rr<2; ++rr) {
        int sg = (c+1)*16 + rp*2 + rr; if (sg > SEQ-1) sg = SEQ-1;
        #pragma unroll
        for (int e=0; e<6; ++e)
          g.v4[rr*6+e] = *(const float4*)&hrow[(long)sg*HDIM + cq*4 + e*128];
      }
    }
    // ---- score MFMA (K-quarter per wave) ----
    {
      f32x4 acc = {0.f,0.f,0.f,0.f};
      #pragma unroll
      for (int kt=0; kt<6; kt++) {
        const int col = w*192 + kt*32 + lg*8;
        uint4 raw = *(const uint4*)&xrow[l15*768 + (col ^ ((l15&7)<<3))];
        union { uint4 q; short8 s8; } A; A.q = raw;
        acc = __builtin_amdgcn_mfma_f32_16x16x32_bf16(A.s8, uf[kt], acc, 0, 0, 0);
      }
      #pragma unroll
      for (int r=0; r<4; ++r) sred[w][lg*4+r][l15] = acc[r];
    }
    barrier_lds();                        // BAR1: sred ready
    // ---- exp on wave 0 only -> wlT ----
    if (w == 0) {
      #pragma unroll
      for (int r=0; r<4; ++r) {
        const int s = lg*4 + r, sg = c*16 + s;
        float S = sred[0][s][l15]+sred[1][s][l15]+sred[2][s][l15]+sred[3][s][l15];
        float al = alpha[sg], be = beta[sg];
        float sc = S + fmaf(cah, al, fmaf(cbh, be, cch)) + pbT[sg*16 + l15];
        float wv = (sg < SEQ && l15 < NH) ? __expf(sc) : 0.f;
        unsigned short wb = f2bf(wv);
        float wr = bf2f(wb);
        rs_p += wr; sa_p = fmaf(wr, al, sa_p); sb_p = fmaf(wr, be, sb_p);
        wlT[l15*16 + s] = wb;
      }
    }
    barrier_lds();                        // BAR2: wlT ready
    // ---- PV MFMA: m^T[j][h] += x^T * w ----
    {
      union { uint4 q; short8 s8; } B; B.q = make_uint4(0,0,0,0);
      if (lg < 2) B.q = *(const uint4*)&wlT[l15*16 + lg*8];
      #pragma unroll
      for (int tau=0; tau<12; ++tau) {
        const int j = w*192 + tau*16 + l15;
        union { uint4 q; short8 s8; } A; A.q = make_uint4(0,0,0,0);
        if (lg < 2) A.q = *(const uint4*)&colT[j*16 + ((lg*8) ^ (((j>>2)&1)<<3))];
        pv[tau] = __builtin_amdgcn_mfma_f32_16x16x32_bf16(A.s8, B.s8, pv[tau], 0, 0, 0);
      }
      // stage next x_row (score(c) done reading since BAR1)
      if (c < 16) {
        #pragma unroll
        for (int rr=0; rr<2; ++rr) {
          const int srow = rp*2+rr;
          #pragma unroll
          for (int e=0; e<6; ++e) {
            float4 v = g.v4[rr*6+e];
            uint2 pk; pk.x = cvt2(v.x,v.y); pk.y = cvt2(v.z,v.w);
            const int cc2 = cq*4 + e*128;
            *(uint2*)&xrow[srow*768 + (cc2 ^ ((srow&7)<<3))] = pk;
          }
        }
      }
    }
    barrier_lds();                        // BAR3: PV done -> colT writable
    if (c < 16) {
      #pragma unroll
      for (int e=0; e<6; ++e)
        #pragma unroll
        for (int d=0; d<4; ++d) {
          const int j = cq*4 + e*128 + d;
          unsigned v = cvt2(g.f[e*4+d], g.f[24+e*4+d]);
          *(unsigned*)&colT[j*16 + ((rp*2) ^ (((j>>2)&1)<<3))] = v;
        }
    }
    // colT writes drain at next BAR1 (before any PV(c+1) read) — safe.
  }

  // ---- softmax sums (wave 0 holds partials over s = lg*4+r) ----
  if (w == 0) {
    rs_p += __shfl_xor(rs_p,16); rs_p += __shfl_xor(rs_p,32);
    sa_p += __shfl_xor(sa_p,16); sa_p += __shfl_xor(sa_p,32);
    sb_p += __shfl_xor(sb_p,16); sb_p += __shfl_xor(sb_p,32);
    if (l < 16) { hsum[0][l15]=rs_p; hsum[1][l15]=sa_p; hsum[2][l15]=sb_p; }
  }
  __syncthreads();

  // ---- m^T regs -> LDS (overlay xbuf), then coalesced epilogue ----
  float* mlds = (float*)xbuf;             // [12][772]
  if (l15 < NH) {
    #pragma unroll
    for (int tau=0; tau<12; ++tau)
      #pragma unroll
      for (int r=0; r<4; ++r) {
        const int j = w*192 + tau*16 + lg*4 + r;
        mlds[l15*772 + j] = pv[tau][r];
      }
  }
  __syncthreads();
  float* mo = mout + (long)bb*(NH*HDIM);
  #pragma unroll
  for (int e=0; e<9; ++e) {
    const int idx = t + 256*e;            // 0..2303
    const int h = idx/192, c4 = (idx%192)*4;
    const float invr = 1.0f/hsum[0][h];
    const float fa = hsum[1][h]*invr, fb = hsum[2][h]*invr;
    float4 mv = *(const float4*)&mlds[h*772 + c4];
    float4 av = *(const float4*)&Av[c4];
    float4 bv4 = *(const float4*)&Bv[c4];
    float4 cv4 = *(const float4*)&Cv[c4];
    float4 o;
    o.x = fmaf(mv.x, invr, fmaf(fa, av.x, fmaf(fb, bv4.x, cv4.x)));
    o.y = fmaf(mv.y, invr, fmaf(fa, av.y, fmaf(fb, bv4.y, cv4.y)));
    o.z = fmaf(mv.z, invr, fmaf(fa, av.z, fmaf(fb, bv4.z, cv4.z)));
    o.w = fmaf(mv.w, invr, fmaf(fa, av.w, fmaf(fb, bv4.w, cv4.w)));
    *(float4*)&mo[h*HDIM + c4] = o;
  }
}

extern "C" void kernel_launch(void* const* d_in, const int* in_sizes, int n_in,
                              void* d_out, int out_size, void* d_ws, size_t ws_size,
                              hipStream_t stream) {
  (void)in_sizes; (void)n_in; (void)out_size;
  const float* hs   = (const float*)d_in[0];
  const float* Wq   = (const float*)d_in[1];
  const float* bq   = (const float*)d_in[2];
  const float* Wk   = (const float*)d_in[3];
  const float* bk   = (const float*)d_in[4];
  const float* Wv   = (const float*)d_in[5];
  const float* bv   = (const float*)d_in[6];
  const float* Wo   = (const float*)d_in[7];
  const float* bo   = (const float*)d_in[8];
  const float* pe_w = (const float*)d_in[9];
  const float* pe_b = (const float*)d_in[10];
  const float* ln_g = (const float*)d_in[11];
  const float* ln_b = (const float*)d_in[12];
  const float* pos_bias = (const float*)d_in[13];
  float* out = (float*)d_out;

  float* wsf   = (float*)d_ws;
  float* pemid = wsf;               // 768
  float* alpha = pemid + 768;       // 288
  float* beta  = alpha + 288;       // 288
  float* Avec  = beta  + 288;       // 768
  float* Bvec  = Avec  + 768;       // 768
  float* Cvec  = Bvec  + 768;       // 768
  float* pbT   = Cvec  + 768;       // 288*16 = 4608
  float* base  = pbT   + 4608;      // fixed total = 8256 floats

  const long perB = 768L + 36L + 9216L + 9216L + 768L;   // q + (ca,cb,cc) + u + m + ctx
  long availF = (long)(ws_size/4) - 8256;
  long chunkB = (availF > 0) ? (availF / perB) : 0;
  if (chunkB > BTOT) chunkB = BTOT;
  chunkB &= ~63L;
  if (chunkB < 64) chunkB = 64;

  float* qb   = base;
  float* cab  = qb  + chunkB*HDIM;
  float* cbb  = cab + chunkB*NH;
  float* ccb  = cbb + chunkB*NH;
  float* ub   = ccb + chunkB*NH;
  float* mb   = ub  + chunkB*(long)NH*HDIM;
  float* ctxb = mb  + chunkB*(long)NH*HDIM;

  k0_pre<<<dim3(1), dim3(256), 0, stream>>>(pe_w, pe_b, ln_g, ln_b, pos_bias,
                                            pemid, alpha, beta, Avec, Bvec, Cvec, pbT);

  for (long b0 = 0; b0 < BTOT; b0 += chunkB) {
    long cbN = (BTOT - b0 < chunkB) ? (BTOT - b0) : chunkB;
    int mt = (int)(cbN/64);
    // K1: q' = 0.125*((hs[:,mid,:] + pe_mid) @ Wq^T + bq)
    gemm64<<<dim3(mt,12,1), dim3(256), 0, stream>>>(
        hs + b0*(long)SEQ*HDIM + (long)MIDP*HDIM, (long)SEQ*HDIM, 0L,
        Wq, (long)HDIM, 0L, 1,
        qb, (long)HDIM, 0L,
        HDIM, bq, 0L, pemid, 0.125f);
    // K2: u'[b,h,:] = q'[b,h,:] @ Wk_h
    gemm64<<<dim3(mt,12,12), dim3(256), 0, stream>>>(
        qb, (long)HDIM, (long)HD,
        Wk, (long)HDIM, (long)HD*HDIM, 0,
        ub, (long)NH*HDIM, (long)HDIM,
        HD, (const float*)nullptr, 0L, (const float*)nullptr, 1.0f);
    // kp: per-(b,h) pe/bias dot scalars
    int nw = (int)(cbN*NH);
    kp<<<dim3((nw+3)/4), dim3(256), 0, stream>>>(qb, ub, bk, Avec, Bvec, Cvec,
                                                 cab, cbb, ccb, (int)cbN);
    // K3: fused MFMA scores + softmax-weighted mean
    k3_v8<<<dim3((int)cbN), dim3(256), 0, stream>>>(
        hs, (int)b0, ub, cab, cbb, ccb, alpha, beta, Avec, Bvec, Cvec, pbT, mb);
    // K4: ctx = Wv_h @ m + bv
    gemm64<<<dim3(mt,1,12), dim3(256), 0, stream>>>(
        mb, (long)NH*HDIM, (long)HDIM,
        Wv, (long)HDIM, (long)HD*HDIM, 1,
        ctxb, (long)HDIM, (long)HD,
        HDIM, bv, (long)HD, (const float*)nullptr, 1.0f);
    // K5: out = ctx @ Wo^T + bo
    gemm64<<<dim3(mt,12,1), dim3(256), 0, stream>>>(
        ctxb, (long)HDIM, 0L,
        Wo, (long)HDIM, 0L, 1,
        out + b0*(long)HDIM, (long)HDIM, 0L,
        HDIM, bo, 0L, (const float*)nullptr, 1.0f);
  }
}

// Round 15
// 619.528 us; speedup vs baseline: 2.2780x; 1.1886x over previous
//
#include <hip/hip_runtime.h>
#include <hip/hip_bf16.h>
#include <math.h>

#define NH   12
#define HD   64
#define HDIM 768
#define SEQ  257
#define MIDP 128
#define BTOT 2048

typedef __attribute__((ext_vector_type(8))) short short8;
typedef __attribute__((ext_vector_type(4))) float f32x4;

__device__ inline unsigned short f2bf(float x){
  union { float f; unsigned u; } v; v.f = x;
  unsigned r = v.u + 0x7FFFu + ((v.u >> 16) & 1u);
  return (unsigned short)(r >> 16);
}
__device__ inline float bf2f(unsigned short h){
  union { unsigned u; float f; } v; v.u = ((unsigned)h) << 16; return v.f;
}
__device__ inline unsigned cvt2(float lo, float hi){
  union { __hip_bfloat162 h; unsigned u; } z;
  z.h = __float22bfloat162_rn(make_float2(lo, hi));   // lo -> low 16 bits
  return z.u;
}
__device__ inline float dot4(float4 a, float4 b){
  return fmaf(a.x,b.x, fmaf(a.y,b.y, fmaf(a.z,b.z, a.w*b.w)));
}
// LDS-only barrier: drain LDS ops, leave global loads in flight
__device__ inline void barrier_lds(){
  __builtin_amdgcn_sched_barrier(0);
  asm volatile("s_waitcnt lgkmcnt(0)" ::: "memory");
  __builtin_amdgcn_s_barrier();
  __builtin_amdgcn_sched_barrier(0);
}

// ---------------- K0: moments + pe rank-3 decomposition tables ----------------
__global__ __launch_bounds__(256) void k0_pre(
    const float* __restrict__ pe_w, const float* __restrict__ pe_b,
    const float* __restrict__ ln_g, const float* __restrict__ ln_b,
    const float* __restrict__ pos_bias,
    float* __restrict__ pemid, float* __restrict__ alpha, float* __restrict__ beta,
    float* __restrict__ Av, float* __restrict__ Bv, float* __restrict__ Cv,
    float* __restrict__ pbT) {
  __shared__ float red[5][256];
  const int t = threadIdx.x;
  float sw=0.f, sb=0.f, sww=0.f, swb=0.f, sbb=0.f;
  for (int j=t; j<HDIM; j+=256) {
    float w=pe_w[j], b=pe_b[j];
    sw+=w; sb+=b; sww+=w*w; swb+=w*b; sbb+=b*b;
  }
  red[0][t]=sw; red[1][t]=sb; red[2][t]=sww; red[3][t]=swb; red[4][t]=sbb;
  __syncthreads();
  for (int off=128; off>0; off>>=1) {
    if (t<off) {
      red[0][t]+=red[0][t+off]; red[1][t]+=red[1][t+off]; red[2][t]+=red[2][t+off];
      red[3][t]+=red[3][t+off]; red[4][t]+=red[4][t+off];
    }
    __syncthreads();
  }
  const float inv = 1.0f/(float)HDIM;
  const float mw=red[0][0]*inv, mc=red[1][0]*inv;
  const float Vw =red[2][0]*inv - mw*mw;
  const float Cwc=red[3][0]*inv - mw*mc;
  const float Vc =red[4][0]*inv - mc*mc;
  for (int s=t; s<288; s+=256) {
    if (s < SEQ) {
      float pos = (float)(s - MIDP) / ((float)MIDP + 1e-6f);
      float var = pos*pos*Vw + 2.f*pos*Cwc + Vc;
      float rstd = rsqrtf(var + 1e-5f);
      alpha[s] = pos*rstd; beta[s] = rstd;
    } else { alpha[s] = 0.f; beta[s] = 0.f; }
  }
  const float rstd0 = rsqrtf(Vc + 1e-5f);
  for (int j=t; j<HDIM; j+=256) {
    float g = ln_g[j];
    Av[j] = (pe_w[j]-mw)*g;
    Bv[j] = (pe_b[j]-mc)*g;
    Cv[j] = ln_b[j];
    pemid[j] = (pe_b[j]-mc)*rstd0*g + ln_b[j];
  }
  for (int i=t; i<288*16; i+=256) {
    int s = i>>4, h = i&15;
    pbT[i] = (s<SEQ && h<NH) ? pos_bias[h*SEQ+s] : 0.f;
  }
}

// ---------------- bf16-MFMA tiled GEMM, 64x64 tile, K-step 32 ----------------
// Same call semantics as the old fp32 gemm64: bT=1: B[n*ldb+k]; bT=0: B[k*ldb+n];
// per-z offsets; avec added to A rows; epilogue (acc+bias)*scale. f32 accumulate.
// LDS rows padded to 40 bf16; slot-XOR (k8 ^ ((row&3)<<3)) -> frag reads and b128
// staging writes are bank-balanced (8-cycle minimum, enumerated).
__global__ __launch_bounds__(256) void gemm64_bf(
    const float* __restrict__ A, long lda, long aoffz,
    const float* __restrict__ Bm, long ldb, long boffz, int bT,
    float* __restrict__ C, long ldc, long coffz,
    int K,
    const float* __restrict__ bias, long biasoffz,
    const float* __restrict__ avec, float scale) {
  __shared__ __align__(16) unsigned short Asb[64*40];   // 5120 B
  __shared__ __align__(16) unsigned short Bsb[64*40];   // 5120 B
  const int t   = threadIdx.x;
  const int l15 = t & 15;
  const int lg  = (t >> 4) & 3;
  const int w   = t >> 6;
  const int z   = blockIdx.z;
  const long n0 = (long)blockIdx.y * 64;
  A  += (long)blockIdx.x*64*lda + (long)z*aoffz;
  Bm += (long)z*boffz;
  C  += (long)blockIdx.x*64*ldc + n0 + (long)z*coffz;

  const int srow = t >> 2;         // staging row 0..63
  const int skk  = (t & 3) * 8;    // k sub-block 0/8/16/24
  const int kB   = t >> 3;         // bT=0: k 0..31
  const int nB   = (t & 7) * 8;    // bT=0: n base

  f32x4 acc[4];
  #pragma unroll
  for (int i=0;i<4;i++){ f32x4 zz={0.f,0.f,0.f,0.f}; acc[i]=zz; }

  for (int k0 = 0; k0 < K; k0 += 32) {
    // ---- stage A (+avec) ----
    {
      const float* p = &A[(long)srow*lda + k0 + skk];
      float4 a0 = *(const float4*)p, a1 = *(const float4*)(p+4);
      if (avec) {
        float4 v0 = *(const float4*)&avec[k0+skk], v1 = *(const float4*)&avec[k0+skk+4];
        a0.x+=v0.x; a0.y+=v0.y; a0.z+=v0.z; a0.w+=v0.w;
        a1.x+=v1.x; a1.y+=v1.y; a1.z+=v1.z; a1.w+=v1.w;
      }
      uint4 pk; pk.x=cvt2(a0.x,a0.y); pk.y=cvt2(a0.z,a0.w);
      pk.z=cvt2(a1.x,a1.y); pk.w=cvt2(a1.z,a1.w);
      *(uint4*)&Asb[srow*40 + (skk ^ ((srow&3)<<3))] = pk;
    }
    // ---- stage B ----
    if (bT) {
      const float* p = &Bm[(long)(n0+srow)*ldb + k0 + skk];
      float4 b0 = *(const float4*)p, b1 = *(const float4*)(p+4);
      uint4 pk; pk.x=cvt2(b0.x,b0.y); pk.y=cvt2(b0.z,b0.w);
      pk.z=cvt2(b1.x,b1.y); pk.w=cvt2(b1.z,b1.w);
      *(uint4*)&Bsb[srow*40 + (skk ^ ((srow&3)<<3))] = pk;
    } else {
      const float* p = &Bm[(long)(k0+kB)*ldb + n0 + nB];
      float4 b0 = *(const float4*)p, b1 = *(const float4*)(p+4);
      const float bv[8] = {b0.x,b0.y,b0.z,b0.w,b1.x,b1.y,b1.z,b1.w};
      #pragma unroll
      for (int i=0;i<8;i++) {
        const int n = nB + i;
        Bsb[n*40 + (kB ^ ((n&3)<<3))] = f2bf(bv[i]);
      }
    }
    __syncthreads();
    // ---- MFMA: wave w -> output rows [w*16, w*16+16), 4 col-tiles ----
    union { uint4 q; short8 s8; } af;
    const int arow = w*16 + l15;
    af.q = *(const uint4*)&Asb[arow*40 + ((lg*8) ^ ((arow&3)<<3))];
    #pragma unroll
    for (int nt=0; nt<4; ++nt) {
      union { uint4 q; short8 s8; } bf_;
      const int brow = nt*16 + l15;
      bf_.q = *(const uint4*)&Bsb[brow*40 + ((lg*8) ^ ((brow&3)<<3))];
      acc[nt] = __builtin_amdgcn_mfma_f32_16x16x32_bf16(af.s8, bf_.s8, acc[nt], 0, 0, 0);
    }
    __syncthreads();
  }
  // ---- epilogue: C[row=w*16+lg*4+r][col=n0+nt*16+l15] ----
  #pragma unroll
  for (int nt=0; nt<4; ++nt) {
    const int col = nt*16 + l15;
    const float bsv = bias ? bias[(long)z*biasoffz + n0 + col] : 0.f;
    #pragma unroll
    for (int r=0; r<4; ++r)
      C[(long)(w*16 + lg*4 + r)*ldc + col] = (acc[nt][r] + bsv)*scale;
  }
}

// ---------------- kp: per-(b,h) scalars ca=u'.A, cb=u'.B, cc=u'.C + q'.bk ----------------
__global__ __launch_bounds__(256) void kp(
    const float* __restrict__ q, const float* __restrict__ u, const float* __restrict__ bk,
    const float* __restrict__ Av, const float* __restrict__ Bv, const float* __restrict__ Cv,
    float* __restrict__ ca, float* __restrict__ cb, float* __restrict__ cc, int nb) {
  const int wid = blockIdx.x*4 + (threadIdx.x >> 6);
  const int lane = threadIdx.x & 63;
  if (wid >= nb*NH) return;
  const int b = wid / NH, h = wid % NH;
  const float* up = u + (long)b*(NH*HDIM) + h*HDIM;
  float pa=0.f, pb_=0.f, pc=0.f;
  #pragma unroll
  for (int e=0;e<3;e++) {
    int c4 = (lane + 64*e)*4;
    float4 uu = *(const float4*)&up[c4];
    pa += dot4(uu, *(const float4*)&Av[c4]);
    pb_+= dot4(uu, *(const float4*)&Bv[c4]);
    pc += dot4(uu, *(const float4*)&Cv[c4]);
  }
  if (lane < 16) {
    float4 qq = *(const float4*)&q[(long)b*HDIM + h*HD + lane*4];
    float4 bb = *(const float4*)&bk[h*HD + lane*4];
    pc += dot4(qq, bb);
  }
  #pragma unroll
  for (int mlog=0; mlog<6; mlog++) {
    int msk = 1<<mlog;
    pa += __shfl_xor(pa, msk);
    pb_+= __shfl_xor(pb_, msk);
    pc += __shfl_xor(pc, msk);
  }
  if (lane == 0) { ca[wid]=pa; cb[wid]=pb_; cc[wid]=pc; }
}

// ---------------- K3 v8 (EXACT round-8 kernel, launch_bounds(256,2)) ----------------
__global__ __launch_bounds__(256, 2) void k3_v8(
    const float* __restrict__ hs, int b0,
    const float* __restrict__ u,
    const float* __restrict__ ca, const float* __restrict__ cb, const float* __restrict__ cc,
    const float* __restrict__ alpha, const float* __restrict__ beta,
    const float* __restrict__ Av, const float* __restrict__ Bv, const float* __restrict__ Cv,
    const float* __restrict__ pbT, float* __restrict__ mout) {
  const int t   = threadIdx.x;
  const int l   = t & 63;
  const int w   = t >> 6;
  const int l15 = l & 15;
  const int lg  = l >> 4;
  const int bb  = blockIdx.x;
  const int b   = b0 + bb;

  __shared__ __align__(16) unsigned short xbuf[2*12288];  // x_row[16*768] | colT[768*16]
  unsigned short* xrow = xbuf;
  unsigned short* colT = xbuf + 12288;
  __shared__ float sred[4][16][17];                       // 4.4 KB
  __shared__ __align__(16) unsigned short wlT[16*16];     // [h][s] bf16, 512 B
  __shared__ float hsum[3][16];

  // u' B-frags (score), wave w covers K-quarter [w*192, +192)
  const float* ub = u + (long)bb*(NH*HDIM);
  short8 uf[6];
  #pragma unroll
  for (int kt=0; kt<6; kt++) {
    union { uint4 q; short8 s8; } s; s.q = make_uint4(0,0,0,0);
    if (l15 < NH) {
      const float* p = ub + l15*HDIM + w*192 + kt*32 + lg*8;
      float4 x0 = *(const float4*)p;
      float4 x1 = *(const float4*)(p+4);
      s.q.x = cvt2(x0.x,x0.y); s.q.y = cvt2(x0.z,x0.w);
      s.q.z = cvt2(x1.x,x1.y); s.q.w = cvt2(x1.z,x1.w);
    }
    uf[kt] = s.s8;
  }
  float cah=0.f, cbh=0.f, cch=0.f;
  if (w==0 && l15<NH) { cah=ca[bb*NH+l15]; cbh=cb[bb*NH+l15]; cch=cc[bb*NH+l15]; }

  f32x4 pv[12];
  #pragma unroll
  for (int i=0;i<12;i++){ f32x4 z={0.f,0.f,0.f,0.f}; pv[i]=z; }
  float rs_p=0.f, sa_p=0.f, sb_p=0.f;

  const float* hrow = hs + (long)b*SEQ*HDIM;
  const int rp = t >> 5;          // 0..7: rows rp*2, rp*2+1
  const int cq = t & 31;          // interleaved col-quads: j = cq*4 + e*128 + d
  union { float4 v4[12]; float f[48]; } g;   // [rr*6+e]

  // chunk-0 load + stage
  #pragma unroll
  for (int rr=0; rr<2; ++rr)
    #pragma unroll
    for (int e=0; e<6; ++e)
      g.v4[rr*6+e] = *(const float4*)&hrow[(long)(rp*2+rr)*HDIM + cq*4 + e*128];
  #pragma unroll
  for (int rr=0; rr<2; ++rr) {
    const int srow = rp*2+rr;
    #pragma unroll
    for (int e=0; e<6; ++e) {
      float4 v = g.v4[rr*6+e];
      uint2 pk; pk.x = cvt2(v.x,v.y); pk.y = cvt2(v.z,v.w);
      const int c = cq*4 + e*128;
      *(uint2*)&xrow[srow*768 + (c ^ ((srow&7)<<3))] = pk;
    }
  }
  #pragma unroll
  for (int e=0; e<6; ++e)
    #pragma unroll
    for (int d=0; d<4; ++d) {
      const int j = cq*4 + e*128 + d;
      unsigned v = cvt2(g.f[e*4+d], g.f[24+e*4+d]);
      *(unsigned*)&colT[j*16 + ((rp*2) ^ (((j>>2)&1)<<3))] = v;
    }
  __syncthreads();

  #pragma unroll 1
  for (int c=0; c<17; ++c) {
    // issue next-chunk loads (ride across lgkm barriers)
    if (c < 16) {
      #pragma unroll
      for (int rr=0; rr<2; ++rr) {
        int sg = (c+1)*16 + rp*2 + rr; if (sg > SEQ-1) sg = SEQ-1;
        #pragma unroll
        for (int e=0; e<6; ++e)
          g.v4[rr*6+e] = *(const float4*)&hrow[(long)sg*HDIM + cq*4 + e*128];
      }
    }
    // ---- score MFMA (K-quarter per wave) ----
    {
      f32x4 acc = {0.f,0.f,0.f,0.f};
      #pragma unroll
      for (int kt=0; kt<6; kt++) {
        const int col = w*192 + kt*32 + lg*8;
        uint4 raw = *(const uint4*)&xrow[l15*768 + (col ^ ((l15&7)<<3))];
        union { uint4 q; short8 s8; } A; A.q = raw;
        acc = __builtin_amdgcn_mfma_f32_16x16x32_bf16(A.s8, uf[kt], acc, 0, 0, 0);
      }
      #pragma unroll
      for (int r=0; r<4; ++r) sred[w][lg*4+r][l15] = acc[r];
    }
    barrier_lds();                        // BAR1: sred ready
    // ---- exp on wave 0 only -> wlT ----
    if (w == 0) {
      #pragma unroll
      for (int r=0; r<4; ++r) {
        const int s = lg*4 + r, sg = c*16 + s;
        float S = sred[0][s][l15]+sred[1][s][l15]+sred[2][s][l15]+sred[3][s][l15];
        float al = alpha[sg], be = beta[sg];
        float sc = S + fmaf(cah, al, fmaf(cbh, be, cch)) + pbT[sg*16 + l15];
        float wv = (sg < SEQ && l15 < NH) ? __expf(sc) : 0.f;
        unsigned short wb = f2bf(wv);
        float wr = bf2f(wb);
        rs_p += wr; sa_p = fmaf(wr, al, sa_p); sb_p = fmaf(wr, be, sb_p);
        wlT[l15*16 + s] = wb;
      }
    }
    barrier_lds();                        // BAR2: wlT ready
    // ---- PV MFMA: m^T[j][h] += x^T * w ----
    {
      union { uint4 q; short8 s8; } B; B.q = make_uint4(0,0,0,0);
      if (lg < 2) B.q = *(const uint4*)&wlT[l15*16 + lg*8];
      #pragma unroll
      for (int tau=0; tau<12; ++tau) {
        const int j = w*192 + tau*16 + l15;
        union { uint4 q; short8 s8; } A; A.q = make_uint4(0,0,0,0);
        if (lg < 2) A.q = *(const uint4*)&colT[j*16 + ((lg*8) ^ (((j>>2)&1)<<3))];
        pv[tau] = __builtin_amdgcn_mfma_f32_16x16x32_bf16(A.s8, B.s8, pv[tau], 0, 0, 0);
      }
      // stage next x_row (score(c) done reading since BAR1)
      if (c < 16) {
        #pragma unroll
        for (int rr=0; rr<2; ++rr) {
          const int srow = rp*2+rr;
          #pragma unroll
          for (int e=0; e<6; ++e) {
            float4 v = g.v4[rr*6+e];
            uint2 pk; pk.x = cvt2(v.x,v.y); pk.y = cvt2(v.z,v.w);
            const int cc2 = cq*4 + e*128;
            *(uint2*)&xrow[srow*768 + (cc2 ^ ((srow&7)<<3))] = pk;
          }
        }
      }
    }
    barrier_lds();                        // BAR3: PV done -> colT writable
    if (c < 16) {
      #pragma unroll
      for (int e=0; e<6; ++e)
        #pragma unroll
        for (int d=0; d<4; ++d) {
          const int j = cq*4 + e*128 + d;
          unsigned v = cvt2(g.f[e*4+d], g.f[24+e*4+d]);
          *(unsigned*)&colT[j*16 + ((rp*2) ^ (((j>>2)&1)<<3))] = v;
        }
    }
    // colT writes drain at next BAR1 (before any PV(c+1) read) — safe.
  }

  // ---- softmax sums (wave 0 holds partials over s = lg*4+r) ----
  if (w == 0) {
    rs_p += __shfl_xor(rs_p,16); rs_p += __shfl_xor(rs_p,32);
    sa_p += __shfl_xor(sa_p,16); sa_p += __shfl_xor(sa_p,32);
    sb_p += __shfl_xor(sb_p,16); sb_p += __shfl_xor(sb_p,32);
    if (l < 16) { hsum[0][l15]=rs_p; hsum[1][l15]=sa_p; hsum[2][l15]=sb_p; }
  }
  __syncthreads();

  // ---- m^T regs -> LDS (overlay xbuf), then coalesced epilogue ----
  float* mlds = (float*)xbuf;             // [12][772]
  if (l15 < NH) {
    #pragma unroll
    for (int tau=0; tau<12; ++tau)
      #pragma unroll
      for (int r=0; r<4; ++r) {
        const int j = w*192 + tau*16 + lg*4 + r;
        mlds[l15*772 + j] = pv[tau][r];
      }
  }
  __syncthreads();
  float* mo = mout + (long)bb*(NH*HDIM);
  #pragma unroll
  for (int e=0; e<9; ++e) {
    const int idx = t + 256*e;            // 0..2303
    const int h = idx/192, c4 = (idx%192)*4;
    const float invr = 1.0f/hsum[0][h];
    const float fa = hsum[1][h]*invr, fb = hsum[2][h]*invr;
    float4 mv = *(const float4*)&mlds[h*772 + c4];
    float4 av = *(const float4*)&Av[c4];
    float4 bv4 = *(const float4*)&Bv[c4];
    float4 cv4 = *(const float4*)&Cv[c4];
    float4 o;
    o.x = fmaf(mv.x, invr, fmaf(fa, av.x, fmaf(fb, bv4.x, cv4.x)));
    o.y = fmaf(mv.y, invr, fmaf(fa, av.y, fmaf(fb, bv4.y, cv4.y)));
    o.z = fmaf(mv.z, invr, fmaf(fa, av.z, fmaf(fb, bv4.z, cv4.z)));
    o.w = fmaf(mv.w, invr, fmaf(fa, av.w, fmaf(fb, bv4.w, cv4.w)));
    *(float4*)&mo[h*HDIM + c4] = o;
  }
}

extern "C" void kernel_launch(void* const* d_in, const int* in_sizes, int n_in,
                              void* d_out, int out_size, void* d_ws, size_t ws_size,
                              hipStream_t stream) {
  (void)in_sizes; (void)n_in; (void)out_size;
  const float* hs   = (const float*)d_in[0];
  const float* Wq   = (const float*)d_in[1];
  const float* bq   = (const float*)d_in[2];
  const float* Wk   = (const float*)d_in[3];
  const float* bk   = (const float*)d_in[4];
  const float* Wv   = (const float*)d_in[5];
  const float* bv   = (const float*)d_in[6];
  const float* Wo   = (const float*)d_in[7];
  const float* bo   = (const float*)d_in[8];
  const float* pe_w = (const float*)d_in[9];
  const float* pe_b = (const float*)d_in[10];
  const float* ln_g = (const float*)d_in[11];
  const float* ln_b = (const float*)d_in[12];
  const float* pos_bias = (const float*)d_in[13];
  float* out = (float*)d_out;

  float* wsf   = (float*)d_ws;
  float* pemid = wsf;               // 768
  float* alpha = pemid + 768;       // 288
  float* beta  = alpha + 288;       // 288
  float* Avec  = beta  + 288;       // 768
  float* Bvec  = Avec  + 768;       // 768
  float* Cvec  = Bvec  + 768;       // 768
  float* pbT   = Cvec  + 768;       // 288*16 = 4608
  float* base  = pbT   + 4608;      // fixed total = 8256 floats

  const long perB = 768L + 36L + 9216L + 9216L + 768L;   // q + (ca,cb,cc) + u + m + ctx
  long availF = (long)(ws_size/4) - 8256;
  long chunkB = (availF > 0) ? (availF / perB) : 0;
  if (chunkB > BTOT) chunkB = BTOT;
  chunkB &= ~63L;
  if (chunkB < 64) chunkB = 64;

  float* qb   = base;
  float* cab  = qb  + chunkB*HDIM;
  float* cbb  = cab + chunkB*NH;
  float* ccb  = cbb + chunkB*NH;
  float* ub   = ccb + chunkB*NH;
  float* mb   = ub  + chunkB*(long)NH*HDIM;
  float* ctxb = mb  + chunkB*(long)NH*HDIM;

  k0_pre<<<dim3(1), dim3(256), 0, stream>>>(pe_w, pe_b, ln_g, ln_b, pos_bias,
                                            pemid, alpha, beta, Avec, Bvec, Cvec, pbT);

  for (long b0 = 0; b0 < BTOT; b0 += chunkB) {
    long cbN = (BTOT - b0 < chunkB) ? (BTOT - b0) : chunkB;
    int mt = (int)(cbN/64);
    // K1: q' = 0.125*((hs[:,mid,:] + pe_mid) @ Wq^T + bq)
    gemm64_bf<<<dim3(mt,12,1), dim3(256), 0, stream>>>(
        hs + b0*(long)SEQ*HDIM + (long)MIDP*HDIM, (long)SEQ*HDIM, 0L,
        Wq, (long)HDIM, 0L, 1,
        qb, (long)HDIM, 0L,
        HDIM, bq, 0L, pemid, 0.125f);
    // K2: u'[b,h,:] = q'[b,h,:] @ Wk_h
    gemm64_bf<<<dim3(mt,12,12), dim3(256), 0, stream>>>(
        qb, (long)HDIM, (long)HD,
        Wk, (long)HDIM, (long)HD*HDIM, 0,
        ub, (long)NH*HDIM, (long)HDIM,
        HD, (const float*)nullptr, 0L, (const float*)nullptr, 1.0f);
    // kp: per-(b,h) pe/bias dot scalars
    int nw = (int)(cbN*NH);
    kp<<<dim3((nw+3)/4), dim3(256), 0, stream>>>(qb, ub, bk, Avec, Bvec, Cvec,
                                                 cab, cbb, ccb, (int)cbN);
    // K3: fused MFMA scores + softmax-weighted mean
    k3_v8<<<dim3((int)cbN), dim3(256), 0, stream>>>(
        hs, (int)b0, ub, cab, cbb, ccb, alpha, beta, Avec, Bvec, Cvec, pbT, mb);
    // K4: ctx = Wv_h @ m + bv
    gemm64_bf<<<dim3(mt,1,12), dim3(256), 0, stream>>>(
        mb, (long)NH*HDIM, (long)HDIM,
        Wv, (long)HDIM, (long)HD*HDIM, 1,
        ctxb, (long)HDIM, (long)HD,
        HDIM, bv, (long)HD, (const float*)nullptr, 1.0f);
    // K5: out = ctx @ Wo^T + bo
    gemm64_bf<<<dim3(mt,12,1), dim3(256), 0, stream>>>(
        ctxb, (long)HDIM, 0L,
        Wo, (long)HDIM, 0L, 1,
        out + b0*(long)HDIM, (long)HDIM, 0L,
        HDIM, bo, 0L, (const float*)nullptr, 1.0f);
  }
}

// Round 16
// 575.202 us; speedup vs baseline: 2.4535x; 1.0771x over previous
//
#include <hip/hip_runtime.h>
#include <hip/hip_bf16.h>
#include <math.h>

#define NH   12
#define HD   64
#define HDIM 768
#define SEQ  257
#define MIDP 128
#define BTOT 2048
#define CTP  18   // colT row pitch in ushorts (16 data + 2 pad -> 36B rows, bank-spread)

typedef __attribute__((ext_vector_type(8))) short short8;
typedef __attribute__((ext_vector_type(4))) float f32x4;

__device__ inline unsigned short f2bf(float x){
  union { float f; unsigned u; } v; v.f = x;
  unsigned r = v.u + 0x7FFFu + ((v.u >> 16) & 1u);
  return (unsigned short)(r >> 16);
}
__device__ inline float bf2f(unsigned short h){
  union { unsigned u; float f; } v; v.u = ((unsigned)h) << 16; return v.f;
}
__device__ inline unsigned cvt2(float lo, float hi){
  union { __hip_bfloat162 h; unsigned u; } z;
  z.h = __float22bfloat162_rn(make_float2(lo, hi));   // lo -> low 16 bits
  return z.u;
}
__device__ inline float dot4(float4 a, float4 b){
  return fmaf(a.x,b.x, fmaf(a.y,b.y, fmaf(a.z,b.z, a.w*b.w)));
}
// LDS-only barrier: drain LDS ops, leave global loads in flight
__device__ inline void barrier_lds(){
  __builtin_amdgcn_sched_barrier(0);
  asm volatile("s_waitcnt lgkmcnt(0)" ::: "memory");
  __builtin_amdgcn_s_barrier();
  __builtin_amdgcn_sched_barrier(0);
}

// ---------------- K0: moments + pe rank-3 decomposition tables ----------------
__global__ __launch_bounds__(256) void k0_pre(
    const float* __restrict__ pe_w, const float* __restrict__ pe_b,
    const float* __restrict__ ln_g, const float* __restrict__ ln_b,
    const float* __restrict__ pos_bias,
    float* __restrict__ pemid, float* __restrict__ alpha, float* __restrict__ beta,
    float* __restrict__ Av, float* __restrict__ Bv, float* __restrict__ Cv,
    float* __restrict__ pbT) {
  __shared__ float red[5][256];
  const int t = threadIdx.x;
  float sw=0.f, sb=0.f, sww=0.f, swb=0.f, sbb=0.f;
  for (int j=t; j<HDIM; j+=256) {
    float w=pe_w[j], b=pe_b[j];
    sw+=w; sb+=b; sww+=w*w; swb+=w*b; sbb+=b*b;
  }
  red[0][t]=sw; red[1][t]=sb; red[2][t]=sww; red[3][t]=swb; red[4][t]=sbb;
  __syncthreads();
  for (int off=128; off>0; off>>=1) {
    if (t<off) {
      red[0][t]+=red[0][t+off]; red[1][t]+=red[1][t+off]; red[2][t]+=red[2][t+off];
      red[3][t]+=red[3][t+off]; red[4][t]+=red[4][t+off];
    }
    __syncthreads();
  }
  const float inv = 1.0f/(float)HDIM;
  const float mw=red[0][0]*inv, mc=red[1][0]*inv;
  const float Vw =red[2][0]*inv - mw*mw;
  const float Cwc=red[3][0]*inv - mw*mc;
  const float Vc =red[4][0]*inv - mc*mc;
  for (int s=t; s<288; s+=256) {
    if (s < SEQ) {
      float pos = (float)(s - MIDP) / ((float)MIDP + 1e-6f);
      float var = pos*pos*Vw + 2.f*pos*Cwc + Vc;
      float rstd = rsqrtf(var + 1e-5f);
      alpha[s] = pos*rstd; beta[s] = rstd;
    } else { alpha[s] = 0.f; beta[s] = 0.f; }
  }
  const float rstd0 = rsqrtf(Vc + 1e-5f);
  for (int j=t; j<HDIM; j+=256) {
    float g = ln_g[j];
    Av[j] = (pe_w[j]-mw)*g;
    Bv[j] = (pe_b[j]-mc)*g;
    Cv[j] = ln_b[j];
    pemid[j] = (pe_b[j]-mc)*rstd0*g + ln_b[j];
  }
  for (int i=t; i<288*16; i+=256) {
    int s = i>>4, h = i&15;
    pbT[i] = (s<SEQ && h<NH) ? pos_bias[h*SEQ+s] : 0.f;
  }
}

// ---------------- bf16-MFMA tiled GEMM, 64x64 tile, K-step 32 ----------------
__global__ __launch_bounds__(256) void gemm64_bf(
    const float* __restrict__ A, long lda, long aoffz,
    const float* __restrict__ Bm, long ldb, long boffz, int bT,
    float* __restrict__ C, long ldc, long coffz,
    int K,
    const float* __restrict__ bias, long biasoffz,
    const float* __restrict__ avec, float scale) {
  __shared__ __align__(16) unsigned short Asb[64*40];   // 5120 B
  __shared__ __align__(16) unsigned short Bsb[64*40];   // 5120 B
  const int t   = threadIdx.x;
  const int l15 = t & 15;
  const int lg  = (t >> 4) & 3;
  const int w   = t >> 6;
  const int z   = blockIdx.z;
  const long n0 = (long)blockIdx.y * 64;
  A  += (long)blockIdx.x*64*lda + (long)z*aoffz;
  Bm += (long)z*boffz;
  C  += (long)blockIdx.x*64*ldc + n0 + (long)z*coffz;

  const int srow = t >> 2;         // staging row 0..63
  const int skk  = (t & 3) * 8;    // k sub-block 0/8/16/24
  const int kB   = t >> 3;         // bT=0: k 0..31
  const int nB   = (t & 7) * 8;    // bT=0: n base

  f32x4 acc[4];
  #pragma unroll
  for (int i=0;i<4;i++){ f32x4 zz={0.f,0.f,0.f,0.f}; acc[i]=zz; }

  for (int k0 = 0; k0 < K; k0 += 32) {
    // ---- stage A (+avec) ----
    {
      const float* p = &A[(long)srow*lda + k0 + skk];
      float4 a0 = *(const float4*)p, a1 = *(const float4*)(p+4);
      if (avec) {
        float4 v0 = *(const float4*)&avec[k0+skk], v1 = *(const float4*)&avec[k0+skk+4];
        a0.x+=v0.x; a0.y+=v0.y; a0.z+=v0.z; a0.w+=v0.w;
        a1.x+=v1.x; a1.y+=v1.y; a1.z+=v1.z; a1.w+=v1.w;
      }
      uint4 pk; pk.x=cvt2(a0.x,a0.y); pk.y=cvt2(a0.z,a0.w);
      pk.z=cvt2(a1.x,a1.y); pk.w=cvt2(a1.z,a1.w);
      *(uint4*)&Asb[srow*40 + (skk ^ ((srow&3)<<3))] = pk;
    }
    // ---- stage B ----
    if (bT) {
      const float* p = &Bm[(long)(n0+srow)*ldb + k0 + skk];
      float4 b0 = *(const float4*)p, b1 = *(const float4*)(p+4);
      uint4 pk; pk.x=cvt2(b0.x,b0.y); pk.y=cvt2(b0.z,b0.w);
      pk.z=cvt2(b1.x,b1.y); pk.w=cvt2(b1.z,b1.w);
      *(uint4*)&Bsb[srow*40 + (skk ^ ((srow&3)<<3))] = pk;
    } else {
      const float* p = &Bm[(long)(k0+kB)*ldb + n0 + nB];
      float4 b0 = *(const float4*)p, b1 = *(const float4*)(p+4);
      const float bv[8] = {b0.x,b0.y,b0.z,b0.w,b1.x,b1.y,b1.z,b1.w};
      #pragma unroll
      for (int i=0;i<8;i++) {
        const int n = nB + i;
        Bsb[n*40 + (kB ^ ((n&3)<<3))] = f2bf(bv[i]);
      }
    }
    __syncthreads();
    // ---- MFMA: wave w -> output rows [w*16, w*16+16), 4 col-tiles ----
    union { uint4 q; short8 s8; } af;
    const int arow = w*16 + l15;
    af.q = *(const uint4*)&Asb[arow*40 + ((lg*8) ^ ((arow&3)<<3))];
    #pragma unroll
    for (int nt=0; nt<4; ++nt) {
      union { uint4 q; short8 s8; } bf_;
      const int brow = nt*16 + l15;
      bf_.q = *(const uint4*)&Bsb[brow*40 + ((lg*8) ^ ((brow&3)<<3))];
      acc[nt] = __builtin_amdgcn_mfma_f32_16x16x32_bf16(af.s8, bf_.s8, acc[nt], 0, 0, 0);
    }
    __syncthreads();
  }
  // ---- epilogue: C[row=w*16+lg*4+r][col=n0+nt*16+l15] ----
  #pragma unroll
  for (int nt=0; nt<4; ++nt) {
    const int col = nt*16 + l15;
    const float bsv = bias ? bias[(long)z*biasoffz + n0 + col] : 0.f;
    #pragma unroll
    for (int r=0; r<4; ++r)
      C[(long)(w*16 + lg*4 + r)*ldc + col] = (acc[nt][r] + bsv)*scale;
  }
}

// ---------------- kp: per-(b,h) scalars ca=u'.A, cb=u'.B, cc=u'.C + q'.bk ----------------
__global__ __launch_bounds__(256) void kp(
    const float* __restrict__ q, const float* __restrict__ u, const float* __restrict__ bk,
    const float* __restrict__ Av, const float* __restrict__ Bv, const float* __restrict__ Cv,
    float* __restrict__ ca, float* __restrict__ cb, float* __restrict__ cc, int nb) {
  const int wid = blockIdx.x*4 + (threadIdx.x >> 6);
  const int lane = threadIdx.x & 63;
  if (wid >= nb*NH) return;
  const int b = wid / NH, h = wid % NH;
  const float* up = u + (long)b*(NH*HDIM) + h*HDIM;
  float pa=0.f, pb_=0.f, pc=0.f;
  #pragma unroll
  for (int e=0;e<3;e++) {
    int c4 = (lane + 64*e)*4;
    float4 uu = *(const float4*)&up[c4];
    pa += dot4(uu, *(const float4*)&Av[c4]);
    pb_+= dot4(uu, *(const float4*)&Bv[c4]);
    pc += dot4(uu, *(const float4*)&Cv[c4]);
  }
  if (lane < 16) {
    float4 qq = *(const float4*)&q[(long)b*HDIM + h*HD + lane*4];
    float4 bb = *(const float4*)&bk[h*HD + lane*4];
    pc += dot4(qq, bb);
  }
  #pragma unroll
  for (int mlog=0; mlog<6; mlog++) {
    int msk = 1<<mlog;
    pa += __shfl_xor(pa, msk);
    pb_+= __shfl_xor(pb_, msk);
    pc += __shfl_xor(pc, msk);
  }
  if (lane == 0) { ca[wid]=pa; cb[wid]=pb_; cc[wid]=pc; }
}

// ---------------- K3 v8c: R8 structure + padded conflict-free colT ----------------
// Identical to the 736-us R8 kernel except colT rows padded 16->18 ushorts (36B):
// write bank = (4cq+9d+rp)%32 -> 4-way (was ~16-way); PV b128 read banks 9*l15%32
// -> 16 distinct -> free. XOR swizzle dropped on both sides (padding replaces it);
// s-order in frags unchanged. LDS 57.3 KB (2 blocks/CU), registers unchanged.
__global__ __launch_bounds__(256, 2) void k3_v8(
    const float* __restrict__ hs, int b0,
    const float* __restrict__ u,
    const float* __restrict__ ca, const float* __restrict__ cb, const float* __restrict__ cc,
    const float* __restrict__ alpha, const float* __restrict__ beta,
    const float* __restrict__ Av, const float* __restrict__ Bv, const float* __restrict__ Cv,
    const float* __restrict__ pbT, float* __restrict__ mout) {
  const int t   = threadIdx.x;
  const int l   = t & 63;
  const int w   = t >> 6;
  const int l15 = l & 15;
  const int lg  = l >> 4;
  const int bb  = blockIdx.x;
  const int b   = b0 + bb;

  __shared__ __align__(16) unsigned short xbuf[12288 + 768*CTP]; // xrow | padded colT
  unsigned short* xrow = xbuf;
  unsigned short* colT = xbuf + 12288;
  __shared__ float sred[4][16][17];                       // 4.4 KB
  __shared__ __align__(16) unsigned short wlT[16*16];     // [h][s] bf16, 512 B
  __shared__ float hsum[3][16];

  // u' B-frags (score), wave w covers K-quarter [w*192, +192)
  const float* ub = u + (long)bb*(NH*HDIM);
  short8 uf[6];
  #pragma unroll
  for (int kt=0; kt<6; kt++) {
    union { uint4 q; short8 s8; } s; s.q = make_uint4(0,0,0,0);
    if (l15 < NH) {
      const float* p = ub + l15*HDIM + w*192 + kt*32 + lg*8;
      float4 x0 = *(const float4*)p;
      float4 x1 = *(const float4*)(p+4);
      s.q.x = cvt2(x0.x,x0.y); s.q.y = cvt2(x0.z,x0.w);
      s.q.z = cvt2(x1.x,x1.y); s.q.w = cvt2(x1.z,x1.w);
    }
    uf[kt] = s.s8;
  }
  float cah=0.f, cbh=0.f, cch=0.f;
  if (w==0 && l15<NH) { cah=ca[bb*NH+l15]; cbh=cb[bb*NH+l15]; cch=cc[bb*NH+l15]; }

  f32x4 pv[12];
  #pragma unroll
  for (int i=0;i<12;i++){ f32x4 z={0.f,0.f,0.f,0.f}; pv[i]=z; }
  float rs_p=0.f, sa_p=0.f, sb_p=0.f;

  const float* hrow = hs + (long)b*SEQ*HDIM;
  const int rp = t >> 5;          // 0..7: rows rp*2, rp*2+1
  const int cq = t & 31;          // interleaved col-quads: j = cq*4 + e*128 + d
  union { float4 v4[12]; float f[48]; } g;   // [rr*6+e]

  // chunk-0 load + stage
  #pragma unroll
  for (int rr=0; rr<2; ++rr)
    #pragma unroll
    for (int e=0; e<6; ++e)
      g.v4[rr*6+e] = *(const float4*)&hrow[(long)(rp*2+rr)*HDIM + cq*4 + e*128];
  #pragma unroll
  for (int rr=0; rr<2; ++rr) {
    const int srow = rp*2+rr;
    #pragma unroll
    for (int e=0; e<6; ++e) {
      float4 v = g.v4[rr*6+e];
      uint2 pk; pk.x = cvt2(v.x,v.y); pk.y = cvt2(v.z,v.w);
      const int c = cq*4 + e*128;
      *(uint2*)&xrow[srow*768 + (c ^ ((srow&7)<<3))] = pk;
    }
  }
  #pragma unroll
  for (int e=0; e<6; ++e)
    #pragma unroll
    for (int d=0; d<4; ++d) {
      const int j = cq*4 + e*128 + d;
      unsigned v = cvt2(g.f[e*4+d], g.f[24+e*4+d]);
      *(unsigned*)&colT[j*CTP + rp*2] = v;
    }
  __syncthreads();

  #pragma unroll 1
  for (int c=0; c<17; ++c) {
    // issue next-chunk loads (ride across lgkm barriers)
    if (c < 16) {
      #pragma unroll
      for (int rr=0; rr<2; ++rr) {
        int sg = (c+1)*16 + rp*2 + rr; if (sg > SEQ-1) sg = SEQ-1;
        #pragma unroll
        for (int e=0; e<6; ++e)
          g.v4[rr*6+e] = *(const float4*)&hrow[(long)sg*HDIM + cq*4 + e*128];
      }
    }
    // ---- score MFMA (K-quarter per wave) ----
    {
      f32x4 acc = {0.f,0.f,0.f,0.f};
      #pragma unroll
      for (int kt=0; kt<6; kt++) {
        const int col = w*192 + kt*32 + lg*8;
        uint4 raw = *(const uint4*)&xrow[l15*768 + (col ^ ((l15&7)<<3))];
        union { uint4 q; short8 s8; } A; A.q = raw;
        acc = __builtin_amdgcn_mfma_f32_16x16x32_bf16(A.s8, uf[kt], acc, 0, 0, 0);
      }
      #pragma unroll
      for (int r=0; r<4; ++r) sred[w][lg*4+r][l15] = acc[r];
    }
    barrier_lds();                        // BAR1: sred ready
    // ---- exp on wave 0 only -> wlT ----
    if (w == 0) {
      #pragma unroll
      for (int r=0; r<4; ++r) {
        const int s = lg*4 + r, sg = c*16 + s;
        float S = sred[0][s][l15]+sred[1][s][l15]+sred[2][s][l15]+sred[3][s][l15];
        float al = alpha[sg], be = beta[sg];
        float sc = S + fmaf(cah, al, fmaf(cbh, be, cch)) + pbT[sg*16 + l15];
        float wv = (sg < SEQ && l15 < NH) ? __expf(sc) : 0.f;
        unsigned short wb = f2bf(wv);
        float wr = bf2f(wb);
        rs_p += wr; sa_p = fmaf(wr, al, sa_p); sb_p = fmaf(wr, be, sb_p);
        wlT[l15*16 + s] = wb;
      }
    }
    barrier_lds();                        // BAR2: wlT ready
    // ---- PV MFMA: m^T[j][h] += x^T * w ----
    {
      union { uint4 q; short8 s8; } B; B.q = make_uint4(0,0,0,0);
      if (lg < 2) B.q = *(const uint4*)&wlT[l15*16 + lg*8];
      #pragma unroll
      for (int tau=0; tau<12; ++tau) {
        const int j = w*192 + tau*16 + l15;
        union { uint4 q; short8 s8; } A; A.q = make_uint4(0,0,0,0);
        if (lg < 2) A.q = *(const uint4*)&colT[j*CTP + lg*8];
        pv[tau] = __builtin_amdgcn_mfma_f32_16x16x32_bf16(A.s8, B.s8, pv[tau], 0, 0, 0);
      }
      // stage next x_row (score(c) done reading since BAR1)
      if (c < 16) {
        #pragma unroll
        for (int rr=0; rr<2; ++rr) {
          const int srow = rp*2+rr;
          #pragma unroll
          for (int e=0; e<6; ++e) {
            float4 v = g.v4[rr*6+e];
            uint2 pk; pk.x = cvt2(v.x,v.y); pk.y = cvt2(v.z,v.w);
            const int cc2 = cq*4 + e*128;
            *(uint2*)&xrow[srow*768 + (cc2 ^ ((srow&7)<<3))] = pk;
          }
        }
      }
    }
    barrier_lds();                        // BAR3: PV done -> colT writable
    if (c < 16) {
      #pragma unroll
      for (int e=0; e<6; ++e)
        #pragma unroll
        for (int d=0; d<4; ++d) {
          const int j = cq*4 + e*128 + d;
          unsigned v = cvt2(g.f[e*4+d], g.f[24+e*4+d]);
          *(unsigned*)&colT[j*CTP + rp*2] = v;
        }
    }
    // colT writes drain at next BAR1 (before any PV(c+1) read) — safe.
  }

  // ---- softmax sums (wave 0 holds partials over s = lg*4+r) ----
  if (w == 0) {
    rs_p += __shfl_xor(rs_p,16); rs_p += __shfl_xor(rs_p,32);
    sa_p += __shfl_xor(sa_p,16); sa_p += __shfl_xor(sa_p,32);
    sb_p += __shfl_xor(sb_p,16); sb_p += __shfl_xor(sb_p,32);
    if (l < 16) { hsum[0][l15]=rs_p; hsum[1][l15]=sa_p; hsum[2][l15]=sb_p; }
  }
  __syncthreads();

  // ---- m^T regs -> LDS (overlay xbuf), then coalesced epilogue ----
  float* mlds = (float*)xbuf;             // [12][772]
  if (l15 < NH) {
    #pragma unroll
    for (int tau=0; tau<12; ++tau)
      #pragma unroll
      for (int r=0; r<4; ++r) {
        const int j = w*192 + tau*16 + lg*4 + r;
        mlds[l15*772 + j] = pv[tau][r];
      }
  }
  __syncthreads();
  float* mo = mout + (long)bb*(NH*HDIM);
  #pragma unroll
  for (int e=0; e<9; ++e) {
    const int idx = t + 256*e;            // 0..2303
    const int h = idx/192, c4 = (idx%192)*4;
    const float invr = 1.0f/hsum[0][h];
    const float fa = hsum[1][h]*invr, fb = hsum[2][h]*invr;
    float4 mv = *(const float4*)&mlds[h*772 + c4];
    float4 av = *(const float4*)&Av[c4];
    float4 bv4 = *(const float4*)&Bv[c4];
    float4 cv4 = *(const float4*)&Cv[c4];
    float4 o;
    o.x = fmaf(mv.x, invr, fmaf(fa, av.x, fmaf(fb, bv4.x, cv4.x)));
    o.y = fmaf(mv.y, invr, fmaf(fa, av.y, fmaf(fb, bv4.y, cv4.y)));
    o.z = fmaf(mv.z, invr, fmaf(fa, av.z, fmaf(fb, bv4.z, cv4.z)));
    o.w = fmaf(mv.w, invr, fmaf(fa, av.w, fmaf(fb, bv4.w, cv4.w)));
    *(float4*)&mo[h*HDIM + c4] = o;
  }
}

extern "C" void kernel_launch(void* const* d_in, const int* in_sizes, int n_in,
                              void* d_out, int out_size, void* d_ws, size_t ws_size,
                              hipStream_t stream) {
  (void)in_sizes; (void)n_in; (void)out_size;
  const float* hs   = (const float*)d_in[0];
  const float* Wq   = (const float*)d_in[1];
  const float* bq   = (const float*)d_in[2];
  const float* Wk   = (const float*)d_in[3];
  const float* bk   = (const float*)d_in[4];
  const float* Wv   = (const float*)d_in[5];
  const float* bv   = (const float*)d_in[6];
  const float* Wo   = (const float*)d_in[7];
  const float* bo   = (const float*)d_in[8];
  const float* pe_w = (const float*)d_in[9];
  const float* pe_b = (const float*)d_in[10];
  const float* ln_g = (const float*)d_in[11];
  const float* ln_b = (const float*)d_in[12];
  const float* pos_bias = (const float*)d_in[13];
  float* out = (float*)d_out;

  float* wsf   = (float*)d_ws;
  float* pemid = wsf;               // 768
  float* alpha = pemid + 768;       // 288
  float* beta  = alpha + 288;       // 288
  float* Avec  = beta  + 288;       // 768
  float* Bvec  = Avec  + 768;       // 768
  float* Cvec  = Bvec  + 768;       // 768
  float* pbT   = Cvec  + 768;       // 288*16 = 4608
  float* base  = pbT   + 4608;      // fixed total = 8256 floats

  const long perB = 768L + 36L + 9216L + 9216L + 768L;   // q + (ca,cb,cc) + u + m + ctx
  long availF = (long)(ws_size/4) - 8256;
  long chunkB = (availF > 0) ? (availF / perB) : 0;
  if (chunkB > BTOT) chunkB = BTOT;
  chunkB &= ~63L;
  if (chunkB < 64) chunkB = 64;

  float* qb   = base;
  float* cab  = qb  + chunkB*HDIM;
  float* cbb  = cab + chunkB*NH;
  float* ccb  = cbb + chunkB*NH;
  float* ub   = ccb + chunkB*NH;
  float* mb   = ub  + chunkB*(long)NH*HDIM;
  float* ctxb = mb  + chunkB*(long)NH*HDIM;

  k0_pre<<<dim3(1), dim3(256), 0, stream>>>(pe_w, pe_b, ln_g, ln_b, pos_bias,
                                            pemid, alpha, beta, Avec, Bvec, Cvec, pbT);

  for (long b0 = 0; b0 < BTOT; b0 += chunkB) {
    long cbN = (BTOT - b0 < chunkB) ? (BTOT - b0) : chunkB;
    int mt = (int)(cbN/64);
    // K1: q' = 0.125*((hs[:,mid,:] + pe_mid) @ Wq^T + bq)
    gemm64_bf<<<dim3(mt,12,1), dim3(256), 0, stream>>>(
        hs + b0*(long)SEQ*HDIM + (long)MIDP*HDIM, (long)SEQ*HDIM, 0L,
        Wq, (long)HDIM, 0L, 1,
        qb, (long)HDIM, 0L,
        HDIM, bq, 0L, pemid, 0.125f);
    // K2: u'[b,h,:] = q'[b,h,:] @ Wk_h
    gemm64_bf<<<dim3(mt,12,12), dim3(256), 0, stream>>>(
        qb, (long)HDIM, (long)HD,
        Wk, (long)HDIM, (long)HD*HDIM, 0,
        ub, (long)NH*HDIM, (long)HDIM,
        HD, (const float*)nullptr, 0L, (const float*)nullptr, 1.0f);
    // kp: per-(b,h) pe/bias dot scalars
    int nw = (int)(cbN*NH);
    kp<<<dim3((nw+3)/4), dim3(256), 0, stream>>>(qb, ub, bk, Avec, Bvec, Cvec,
                                                 cab, cbb, ccb, (int)cbN);
    // K3: fused MFMA scores + softmax-weighted mean
    k3_v8<<<dim3((int)cbN), dim3(256), 0, stream>>>(
        hs, (int)b0, ub, cab, cbb, ccb, alpha, beta, Avec, Bvec, Cvec, pbT, mb);
    // K4: ctx = Wv_h @ m + bv
    gemm64_bf<<<dim3(mt,1,12), dim3(256), 0, stream>>>(
        mb, (long)NH*HDIM, (long)HDIM,
        Wv, (long)HDIM, (long)HD*HDIM, 1,
        ctxb, (long)HDIM, (long)HD,
        HDIM, bv, (long)HD, (const float*)nullptr, 1.0f);
    // K5: out = ctx @ Wo^T + bo
    gemm64_bf<<<dim3(mt,12,1), dim3(256), 0, stream>>>(
        ctxb, (long)HDIM, 0L,
        Wo, (long)HDIM, 0L, 1,
        out + b0*(long)HDIM, (long)HDIM, 0L,
        HDIM, bo, 0L, (const float*)nullptr, 1.0f);
  }
}

// Round 17
// 551.701 us; speedup vs baseline: 2.5581x; 1.0426x over previous
//
#include <hip/hip_runtime.h>
#include <hip/hip_bf16.h>
#include <math.h>

#define NH   12
#define HD   64
#define HDIM 768
#define SEQ  257
#define MIDP 128
#define BTOT 2048
#define CTP  18   // colT row pitch in ushorts (16 data + 2 pad -> 36B rows, bank-spread)

typedef __attribute__((ext_vector_type(8))) short short8;
typedef __attribute__((ext_vector_type(4))) float f32x4;

__device__ inline unsigned short f2bf(float x){
  union { float f; unsigned u; } v; v.f = x;
  unsigned r = v.u + 0x7FFFu + ((v.u >> 16) & 1u);
  return (unsigned short)(r >> 16);
}
__device__ inline float bf2f(unsigned short h){
  union { unsigned u; float f; } v; v.u = ((unsigned)h) << 16; return v.f;
}
__device__ inline unsigned cvt2(float lo, float hi){
  union { __hip_bfloat162 h; unsigned u; } z;
  z.h = __float22bfloat162_rn(make_float2(lo, hi));   // lo -> low 16 bits
  return z.u;
}
__device__ inline float dot4(float4 a, float4 b){
  return fmaf(a.x,b.x, fmaf(a.y,b.y, fmaf(a.z,b.z, a.w*b.w)));
}
// LDS-only barrier: drain LDS ops, leave global loads in flight
__device__ inline void barrier_lds(){
  __builtin_amdgcn_sched_barrier(0);
  asm volatile("s_waitcnt lgkmcnt(0)" ::: "memory");
  __builtin_amdgcn_s_barrier();
  __builtin_amdgcn_sched_barrier(0);
}

// ---------------- K0: moments + pe rank-3 decomposition tables ----------------
__global__ __launch_bounds__(256) void k0_pre(
    const float* __restrict__ pe_w, const float* __restrict__ pe_b,
    const float* __restrict__ ln_g, const float* __restrict__ ln_b,
    const float* __restrict__ pos_bias,
    float* __restrict__ pemid, float* __restrict__ alpha, float* __restrict__ beta,
    float* __restrict__ Av, float* __restrict__ Bv, float* __restrict__ Cv,
    float* __restrict__ pbT) {
  __shared__ float red[5][256];
  const int t = threadIdx.x;
  float sw=0.f, sb=0.f, sww=0.f, swb=0.f, sbb=0.f;
  for (int j=t; j<HDIM; j+=256) {
    float w=pe_w[j], b=pe_b[j];
    sw+=w; sb+=b; sww+=w*w; swb+=w*b; sbb+=b*b;
  }
  red[0][t]=sw; red[1][t]=sb; red[2][t]=sww; red[3][t]=swb; red[4][t]=sbb;
  __syncthreads();
  for (int off=128; off>0; off>>=1) {
    if (t<off) {
      red[0][t]+=red[0][t+off]; red[1][t]+=red[1][t+off]; red[2][t]+=red[2][t+off];
      red[3][t]+=red[3][t+off]; red[4][t]+=red[4][t+off];
    }
    __syncthreads();
  }
  const float inv = 1.0f/(float)HDIM;
  const float mw=red[0][0]*inv, mc=red[1][0]*inv;
  const float Vw =red[2][0]*inv - mw*mw;
  const float Cwc=red[3][0]*inv - mw*mc;
  const float Vc =red[4][0]*inv - mc*mc;
  for (int s=t; s<288; s+=256) {
    if (s < SEQ) {
      float pos = (float)(s - MIDP) / ((float)MIDP + 1e-6f);
      float var = pos*pos*Vw + 2.f*pos*Cwc + Vc;
      float rstd = rsqrtf(var + 1e-5f);
      alpha[s] = pos*rstd; beta[s] = rstd;
    } else { alpha[s] = 0.f; beta[s] = 0.f; }
  }
  const float rstd0 = rsqrtf(Vc + 1e-5f);
  for (int j=t; j<HDIM; j+=256) {
    float g = ln_g[j];
    Av[j] = (pe_w[j]-mw)*g;
    Bv[j] = (pe_b[j]-mc)*g;
    Cv[j] = ln_b[j];
    pemid[j] = (pe_b[j]-mc)*rstd0*g + ln_b[j];
  }
  for (int i=t; i<288*16; i+=256) {
    int s = i>>4, h = i&15;
    pbT[i] = (s<SEQ && h<NH) ? pos_bias[h*SEQ+s] : 0.f;
  }
}

// ---------------- bf16-MFMA tiled GEMM, 64x64 tile, K-step 32 ----------------
__global__ __launch_bounds__(256) void gemm64_bf(
    const float* __restrict__ A, long lda, long aoffz,
    const float* __restrict__ Bm, long ldb, long boffz, int bT,
    float* __restrict__ C, long ldc, long coffz,
    int K,
    const float* __restrict__ bias, long biasoffz,
    const float* __restrict__ avec, float scale) {
  __shared__ __align__(16) unsigned short Asb[64*40];   // 5120 B
  __shared__ __align__(16) unsigned short Bsb[64*40];   // 5120 B
  const int t   = threadIdx.x;
  const int l15 = t & 15;
  const int lg  = (t >> 4) & 3;
  const int w   = t >> 6;
  const int z   = blockIdx.z;
  const long n0 = (long)blockIdx.y * 64;
  A  += (long)blockIdx.x*64*lda + (long)z*aoffz;
  Bm += (long)z*boffz;
  C  += (long)blockIdx.x*64*ldc + n0 + (long)z*coffz;

  const int srow = t >> 2;         // staging row 0..63
  const int skk  = (t & 3) * 8;    // k sub-block 0/8/16/24
  const int kB   = t >> 3;         // bT=0: k 0..31
  const int nB   = (t & 7) * 8;    // bT=0: n base

  f32x4 acc[4];
  #pragma unroll
  for (int i=0;i<4;i++){ f32x4 zz={0.f,0.f,0.f,0.f}; acc[i]=zz; }

  for (int k0 = 0; k0 < K; k0 += 32) {
    // ---- stage A (+avec) ----
    {
      const float* p = &A[(long)srow*lda + k0 + skk];
      float4 a0 = *(const float4*)p, a1 = *(const float4*)(p+4);
      if (avec) {
        float4 v0 = *(const float4*)&avec[k0+skk], v1 = *(const float4*)&avec[k0+skk+4];
        a0.x+=v0.x; a0.y+=v0.y; a0.z+=v0.z; a0.w+=v0.w;
        a1.x+=v1.x; a1.y+=v1.y; a1.z+=v1.z; a1.w+=v1.w;
      }
      uint4 pk; pk.x=cvt2(a0.x,a0.y); pk.y=cvt2(a0.z,a0.w);
      pk.z=cvt2(a1.x,a1.y); pk.w=cvt2(a1.z,a1.w);
      *(uint4*)&Asb[srow*40 + (skk ^ ((srow&3)<<3))] = pk;
    }
    // ---- stage B ----
    if (bT) {
      const float* p = &Bm[(long)(n0+srow)*ldb + k0 + skk];
      float4 b0 = *(const float4*)p, b1 = *(const float4*)(p+4);
      uint4 pk; pk.x=cvt2(b0.x,b0.y); pk.y=cvt2(b0.z,b0.w);
      pk.z=cvt2(b1.x,b1.y); pk.w=cvt2(b1.z,b1.w);
      *(uint4*)&Bsb[srow*40 + (skk ^ ((srow&3)<<3))] = pk;
    } else {
      const float* p = &Bm[(long)(k0+kB)*ldb + n0 + nB];
      float4 b0 = *(const float4*)p, b1 = *(const float4*)(p+4);
      const float bv[8] = {b0.x,b0.y,b0.z,b0.w,b1.x,b1.y,b1.z,b1.w};
      #pragma unroll
      for (int i=0;i<8;i++) {
        const int n = nB + i;
        Bsb[n*40 + (kB ^ ((n&3)<<3))] = f2bf(bv[i]);
      }
    }
    __syncthreads();
    // ---- MFMA: wave w -> output rows [w*16, w*16+16), 4 col-tiles ----
    union { uint4 q; short8 s8; } af;
    const int arow = w*16 + l15;
    af.q = *(const uint4*)&Asb[arow*40 + ((lg*8) ^ ((arow&3)<<3))];
    #pragma unroll
    for (int nt=0; nt<4; ++nt) {
      union { uint4 q; short8 s8; } bf_;
      const int brow = nt*16 + l15;
      bf_.q = *(const uint4*)&Bsb[brow*40 + ((lg*8) ^ ((brow&3)<<3))];
      acc[nt] = __builtin_amdgcn_mfma_f32_16x16x32_bf16(af.s8, bf_.s8, acc[nt], 0, 0, 0);
    }
    __syncthreads();
  }
  // ---- epilogue: C[row=w*16+lg*4+r][col=n0+nt*16+l15] ----
  #pragma unroll
  for (int nt=0; nt<4; ++nt) {
    const int col = nt*16 + l15;
    const float bsv = bias ? bias[(long)z*biasoffz + n0 + col] : 0.f;
    #pragma unroll
    for (int r=0; r<4; ++r)
      C[(long)(w*16 + lg*4 + r)*ldc + col] = (acc[nt][r] + bsv)*scale;
  }
}

// ---------------- kp: per-(b,h) scalars ca=u'.A, cb=u'.B, cc=u'.C + q'.bk ----------------
__global__ __launch_bounds__(256) void kp(
    const float* __restrict__ q, const float* __restrict__ u, const float* __restrict__ bk,
    const float* __restrict__ Av, const float* __restrict__ Bv, const float* __restrict__ Cv,
    float* __restrict__ ca, float* __restrict__ cb, float* __restrict__ cc, int nb) {
  const int wid = blockIdx.x*4 + (threadIdx.x >> 6);
  const int lane = threadIdx.x & 63;
  if (wid >= nb*NH) return;
  const int b = wid / NH, h = wid % NH;
  const float* up = u + (long)b*(NH*HDIM) + h*HDIM;
  float pa=0.f, pb_=0.f, pc=0.f;
  #pragma unroll
  for (int e=0;e<3;e++) {
    int c4 = (lane + 64*e)*4;
    float4 uu = *(const float4*)&up[c4];
    pa += dot4(uu, *(const float4*)&Av[c4]);
    pb_+= dot4(uu, *(const float4*)&Bv[c4]);
    pc += dot4(uu, *(const float4*)&Cv[c4]);
  }
  if (lane < 16) {
    float4 qq = *(const float4*)&q[(long)b*HDIM + h*HD + lane*4];
    float4 bb = *(const float4*)&bk[h*HD + lane*4];
    pc += dot4(qq, bb);
  }
  #pragma unroll
  for (int mlog=0; mlog<6; mlog++) {
    int msk = 1<<mlog;
    pa += __shfl_xor(pa, msk);
    pb_+= __shfl_xor(pb_, msk);
    pc += __shfl_xor(pc, msk);
  }
  if (lane == 0) { ca[wid]=pa; cb[wid]=pb_; cc[wid]=pc; }
}

// ---------------- K3 v8d: 2 barriers/chunk via redundant per-wave exp ----------------
// R16 structure, but wlT is deleted: after BAR1 every lane with lg<2 computes its own
// PV B-fragment (8 exps from sred + LDS alpha/beta + prefetched pbT) bit-identically.
// Barriers/chunk 3 -> 2. Hazards: sred(c+1) written after BAR2(c) (>= all PV reads);
// xrow(c+1) staged in PV region, drains at BAR2; colT(c+1) after BAR2, drains at
// BAR1(c+1). alpha/beta cached in LDS; pbT prefetched at chunk top.
__global__ __launch_bounds__(256, 2) void k3_v8(
    const float* __restrict__ hs, int b0,
    const float* __restrict__ u,
    const float* __restrict__ ca, const float* __restrict__ cb, const float* __restrict__ cc,
    const float* __restrict__ alpha, const float* __restrict__ beta,
    const float* __restrict__ Av, const float* __restrict__ Bv, const float* __restrict__ Cv,
    const float* __restrict__ pbT, float* __restrict__ mout) {
  const int t   = threadIdx.x;
  const int l   = t & 63;
  const int w   = t >> 6;
  const int l15 = l & 15;
  const int lg  = l >> 4;
  const int bb  = blockIdx.x;
  const int b   = b0 + bb;

  __shared__ __align__(16) unsigned short xbuf[12288 + 768*CTP]; // xrow | padded colT
  unsigned short* xrow = xbuf;
  unsigned short* colT = xbuf + 12288;
  __shared__ float sred[4][16][17];                       // 4.4 KB
  __shared__ float al_s[288], be_s[288];                  // 2.3 KB
  __shared__ float hsum[3][16];

  for (int i=t; i<288; i+=256) { al_s[i]=alpha[i]; be_s[i]=beta[i]; }

  // u' B-frags (score), wave w covers K-quarter [w*192, +192)
  const float* ub = u + (long)bb*(NH*HDIM);
  short8 uf[6];
  #pragma unroll
  for (int kt=0; kt<6; kt++) {
    union { uint4 q; short8 s8; } s; s.q = make_uint4(0,0,0,0);
    if (l15 < NH) {
      const float* p = ub + l15*HDIM + w*192 + kt*32 + lg*8;
      float4 x0 = *(const float4*)p;
      float4 x1 = *(const float4*)(p+4);
      s.q.x = cvt2(x0.x,x0.y); s.q.y = cvt2(x0.z,x0.w);
      s.q.z = cvt2(x1.x,x1.y); s.q.w = cvt2(x1.z,x1.w);
    }
    uf[kt] = s.s8;
  }
  // per-(b,h) affine scalars: needed by ALL waves now (redundant exp)
  float cah=0.f, cbh=0.f, cch=0.f;
  if (l15 < NH) { cah=ca[bb*NH+l15]; cbh=cb[bb*NH+l15]; cch=cc[bb*NH+l15]; }

  f32x4 pv[12];
  #pragma unroll
  for (int i=0;i<12;i++){ f32x4 z={0.f,0.f,0.f,0.f}; pv[i]=z; }
  float rs_p=0.f, sa_p=0.f, sb_p=0.f;     // accumulated on wave 0 (lg<2) only

  const float* hrow = hs + (long)b*SEQ*HDIM;
  const int rp = t >> 5;          // 0..7: rows rp*2, rp*2+1
  const int cq = t & 31;          // interleaved col-quads: j = cq*4 + e*128 + d
  union { float4 v4[12]; float f[48]; } g;   // [rr*6+e]

  // chunk-0 load + stage
  #pragma unroll
  for (int rr=0; rr<2; ++rr)
    #pragma unroll
    for (int e=0; e<6; ++e)
      g.v4[rr*6+e] = *(const float4*)&hrow[(long)(rp*2+rr)*HDIM + cq*4 + e*128];
  #pragma unroll
  for (int rr=0; rr<2; ++rr) {
    const int srow = rp*2+rr;
    #pragma unroll
    for (int e=0; e<6; ++e) {
      float4 v = g.v4[rr*6+e];
      uint2 pk; pk.x = cvt2(v.x,v.y); pk.y = cvt2(v.z,v.w);
      const int c = cq*4 + e*128;
      *(uint2*)&xrow[srow*768 + (c ^ ((srow&7)<<3))] = pk;
    }
  }
  #pragma unroll
  for (int e=0; e<6; ++e)
    #pragma unroll
    for (int d=0; d<4; ++d) {
      const int j = cq*4 + e*128 + d;
      unsigned v = cvt2(g.f[e*4+d], g.f[24+e*4+d]);
      *(unsigned*)&colT[j*CTP + rp*2] = v;
    }
  __syncthreads();

  #pragma unroll 1
  for (int c=0; c<17; ++c) {
    // ---- pbT prefetch for this chunk's exp (lg<2 lanes, all waves) ----
    float pb_r[8];
    if (lg < 2) {
      #pragma unroll
      for (int e=0; e<8; ++e)
        pb_r[e] = pbT[(c*16 + lg*8 + e)*16 + l15];
    }
    // ---- issue next-chunk loads (ride across lgkm barriers) ----
    if (c < 16) {
      #pragma unroll
      for (int rr=0; rr<2; ++rr) {
        int sg = (c+1)*16 + rp*2 + rr; if (sg > SEQ-1) sg = SEQ-1;
        #pragma unroll
        for (int e=0; e<6; ++e)
          g.v4[rr*6+e] = *(const float4*)&hrow[(long)sg*HDIM + cq*4 + e*128];
      }
    }
    // ---- score MFMA (K-quarter per wave) ----
    {
      f32x4 acc = {0.f,0.f,0.f,0.f};
      #pragma unroll
      for (int kt=0; kt<6; kt++) {
        const int col = w*192 + kt*32 + lg*8;
        uint4 raw = *(const uint4*)&xrow[l15*768 + (col ^ ((l15&7)<<3))];
        union { uint4 q; short8 s8; } A; A.q = raw;
        acc = __builtin_amdgcn_mfma_f32_16x16x32_bf16(A.s8, uf[kt], acc, 0, 0, 0);
      }
      #pragma unroll
      for (int r=0; r<4; ++r) sred[w][lg*4+r][l15] = acc[r];
    }
    barrier_lds();                        // BAR1: sred ready, xrow(c) free
    // ---- redundant exp -> PV B-frag in registers (lg<2 lanes, all waves) ----
    union { uint4 q; short8 s8; } B; B.q = make_uint4(0,0,0,0);
    if (lg < 2) {
      #pragma unroll
      for (int e=0; e<8; ++e) {
        const int s = lg*8 + e, sg = c*16 + s;
        float S = sred[0][s][l15]+sred[1][s][l15]+sred[2][s][l15]+sred[3][s][l15];
        float al = al_s[sg], be = be_s[sg];
        float sc = S + fmaf(cah, al, fmaf(cbh, be, cch)) + pb_r[e];
        float wv = (sg < SEQ && l15 < NH) ? __expf(sc) : 0.f;
        unsigned short wb = f2bf(wv);
        B.s8[e] = (short)wb;
        if (w == 0) {
          float wr = bf2f(wb);
          rs_p += wr; sa_p = fmaf(wr, al, sa_p); sb_p = fmaf(wr, be, sb_p);
        }
      }
    }
    // ---- PV MFMA: m^T[j][h] += x^T * w ----
    {
      #pragma unroll
      for (int tau=0; tau<12; ++tau) {
        const int j = w*192 + tau*16 + l15;
        union { uint4 q; short8 s8; } A; A.q = make_uint4(0,0,0,0);
        if (lg < 2) A.q = *(const uint4*)&colT[j*CTP + lg*8];
        pv[tau] = __builtin_amdgcn_mfma_f32_16x16x32_bf16(A.s8, B.s8, pv[tau], 0, 0, 0);
      }
      // stage next x_row (score(c) done reading since BAR1)
      if (c < 16) {
        #pragma unroll
        for (int rr=0; rr<2; ++rr) {
          const int srow = rp*2+rr;
          #pragma unroll
          for (int e=0; e<6; ++e) {
            float4 v = g.v4[rr*6+e];
            uint2 pk; pk.x = cvt2(v.x,v.y); pk.y = cvt2(v.z,v.w);
            const int cc2 = cq*4 + e*128;
            *(uint2*)&xrow[srow*768 + (cc2 ^ ((srow&7)<<3))] = pk;
          }
        }
      }
    }
    barrier_lds();                        // BAR2: PV done, xrow(c+1) drained
    // ---- stage colT(c+1); drains at BAR1(c+1), before PV(c+1) reads ----
    if (c < 16) {
      #pragma unroll
      for (int e=0; e<6; ++e)
        #pragma unroll
        for (int d=0; d<4; ++d) {
          const int j = cq*4 + e*128 + d;
          unsigned v = cvt2(g.f[e*4+d], g.f[24+e*4+d]);
          *(unsigned*)&colT[j*CTP + rp*2] = v;
        }
    }
    // sred(c+1) written after BAR2 (score phase) >= all PV-phase sred reads. Safe.
  }

  // ---- softmax sums (wave 0, lg<2 lanes hold partials; xor over lg sums them) ----
  if (w == 0) {
    rs_p += __shfl_xor(rs_p,16); rs_p += __shfl_xor(rs_p,32);
    sa_p += __shfl_xor(sa_p,16); sa_p += __shfl_xor(sa_p,32);
    sb_p += __shfl_xor(sb_p,16); sb_p += __shfl_xor(sb_p,32);
    if (l < 16) { hsum[0][l15]=rs_p; hsum[1][l15]=sa_p; hsum[2][l15]=sb_p; }
  }
  __syncthreads();

  // ---- m^T regs -> LDS (overlay xbuf), then coalesced epilogue ----
  float* mlds = (float*)xbuf;             // [12][772]
  if (l15 < NH) {
    #pragma unroll
    for (int tau=0; tau<12; ++tau)
      #pragma unroll
      for (int r=0; r<4; ++r) {
        const int j = w*192 + tau*16 + lg*4 + r;
        mlds[l15*772 + j] = pv[tau][r];
      }
  }
  __syncthreads();
  float* mo = mout + (long)bb*(NH*HDIM);
  #pragma unroll
  for (int e=0; e<9; ++e) {
    const int idx = t + 256*e;            // 0..2303
    const int h = idx/192, c4 = (idx%192)*4;
    const float invr = 1.0f/hsum[0][h];
    const float fa = hsum[1][h]*invr, fb = hsum[2][h]*invr;
    float4 mv = *(const float4*)&mlds[h*772 + c4];
    float4 av = *(const float4*)&Av[c4];
    float4 bv4 = *(const float4*)&Bv[c4];
    float4 cv4 = *(const float4*)&Cv[c4];
    float4 o;
    o.x = fmaf(mv.x, invr, fmaf(fa, av.x, fmaf(fb, bv4.x, cv4.x)));
    o.y = fmaf(mv.y, invr, fmaf(fa, av.y, fmaf(fb, bv4.y, cv4.y)));
    o.z = fmaf(mv.z, invr, fmaf(fa, av.z, fmaf(fb, bv4.z, cv4.z)));
    o.w = fmaf(mv.w, invr, fmaf(fa, av.w, fmaf(fb, bv4.w, cv4.w)));
    *(float4*)&mo[h*HDIM + c4] = o;
  }
}

extern "C" void kernel_launch(void* const* d_in, const int* in_sizes, int n_in,
                              void* d_out, int out_size, void* d_ws, size_t ws_size,
                              hipStream_t stream) {
  (void)in_sizes; (void)n_in; (void)out_size;
  const float* hs   = (const float*)d_in[0];
  const float* Wq   = (const float*)d_in[1];
  const float* bq   = (const float*)d_in[2];
  const float* Wk   = (const float*)d_in[3];
  const float* bk   = (const float*)d_in[4];
  const float* Wv   = (const float*)d_in[5];
  const float* bv   = (const float*)d_in[6];
  const float* Wo   = (const float*)d_in[7];
  const float* bo   = (const float*)d_in[8];
  const float* pe_w = (const float*)d_in[9];
  const float* pe_b = (const float*)d_in[10];
  const float* ln_g = (const float*)d_in[11];
  const float* ln_b = (const float*)d_in[12];
  const float* pos_bias = (const float*)d_in[13];
  float* out = (float*)d_out;

  float* wsf   = (float*)d_ws;
  float* pemid = wsf;               // 768
  float* alpha = pemid + 768;       // 288
  float* beta  = alpha + 288;       // 288
  float* Avec  = beta  + 288;       // 768
  float* Bvec  = Avec  + 768;       // 768
  float* Cvec  = Bvec  + 768;       // 768
  float* pbT   = Cvec  + 768;       // 288*16 = 4608
  float* base  = pbT   + 4608;      // fixed total = 8256 floats

  const long perB = 768L + 36L + 9216L + 9216L + 768L;   // q + (ca,cb,cc) + u + m + ctx
  long availF = (long)(ws_size/4) - 8256;
  long chunkB = (availF > 0) ? (availF / perB) : 0;
  if (chunkB > BTOT) chunkB = BTOT;
  chunkB &= ~63L;
  if (chunkB < 64) chunkB = 64;

  float* qb   = base;
  float* cab  = qb  + chunkB*HDIM;
  float* cbb  = cab + chunkB*NH;
  float* ccb  = cbb + chunkB*NH;
  float* ub   = ccb + chunkB*NH;
  float* mb   = ub  + chunkB*(long)NH*HDIM;
  float* ctxb = mb  + chunkB*(long)NH*HDIM;

  k0_pre<<<dim3(1), dim3(256), 0, stream>>>(pe_w, pe_b, ln_g, ln_b, pos_bias,
                                            pemid, alpha, beta, Avec, Bvec, Cvec, pbT);

  for (long b0 = 0; b0 < BTOT; b0 += chunkB) {
    long cbN = (BTOT - b0 < chunkB) ? (BTOT - b0) : chunkB;
    int mt = (int)(cbN/64);
    // K1: q' = 0.125*((hs[:,mid,:] + pe_mid) @ Wq^T + bq)
    gemm64_bf<<<dim3(mt,12,1), dim3(256), 0, stream>>>(
        hs + b0*(long)SEQ*HDIM + (long)MIDP*HDIM, (long)SEQ*HDIM, 0L,
        Wq, (long)HDIM, 0L, 1,
        qb, (long)HDIM, 0L,
        HDIM, bq, 0L, pemid, 0.125f);
    // K2: u'[b,h,:] = q'[b,h,:] @ Wk_h
    gemm64_bf<<<dim3(mt,12,12), dim3(256), 0, stream>>>(
        qb, (long)HDIM, (long)HD,
        Wk, (long)HDIM, (long)HD*HDIM, 0,
        ub, (long)NH*HDIM, (long)HDIM,
        HD, (const float*)nullptr, 0L, (const float*)nullptr, 1.0f);
    // kp: per-(b,h) pe/bias dot scalars
    int nw = (int)(cbN*NH);
    kp<<<dim3((nw+3)/4), dim3(256), 0, stream>>>(qb, ub, bk, Avec, Bvec, Cvec,
                                                 cab, cbb, ccb, (int)cbN);
    // K3: fused MFMA scores + softmax-weighted mean
    k3_v8<<<dim3((int)cbN), dim3(256), 0, stream>>>(
        hs, (int)b0, ub, cab, cbb, ccb, alpha, beta, Avec, Bvec, Cvec, pbT, mb);
    // K4: ctx = Wv_h @ m + bv
    gemm64_bf<<<dim3(mt,1,12), dim3(256), 0, stream>>>(
        mb, (long)NH*HDIM, (long)HDIM,
        Wv, (long)HDIM, (long)HD*HDIM, 1,
        ctxb, (long)HDIM, (long)HD,
        HDIM, bv, (long)HD, (const float*)nullptr, 1.0f);
    // K5: out = ctx @ Wo^T + bo
    gemm64_bf<<<dim3(mt,12,1), dim3(256), 0, stream>>>(
        ctxb, (long)HDIM, 0L,
        Wo, (long)HDIM, 0L, 1,
        out + b0*(long)HDIM, (long)HDIM, 0L,
        HDIM, bo, 0L, (const float*)nullptr, 1.0f);
  }
}

// Round 18
// 528.240 us; speedup vs baseline: 2.6717x; 1.0444x over previous
//
#include <hip/hip_runtime.h>
#include <hip/hip_bf16.h>
#include <math.h>

#define NH   12
#define HD   64
#define HDIM 768
#define SEQ  257
#define MIDP 128
#define BTOT 2048
#define CTP  18   // colT row pitch in ushorts (16 data + 2 pad -> 36B rows, bank-spread)

typedef __attribute__((ext_vector_type(8))) short short8;
typedef __attribute__((ext_vector_type(4))) float f32x4;

__device__ inline unsigned short f2bf(float x){
  union { float f; unsigned u; } v; v.f = x;
  unsigned r = v.u + 0x7FFFu + ((v.u >> 16) & 1u);
  return (unsigned short)(r >> 16);
}
__device__ inline float bf2f(unsigned short h){
  union { unsigned u; float f; } v; v.u = ((unsigned)h) << 16; return v.f;
}
__device__ inline unsigned cvt2(float lo, float hi){
  union { __hip_bfloat162 h; unsigned u; } z;
  z.h = __float22bfloat162_rn(make_float2(lo, hi));   // lo -> low 16 bits
  return z.u;
}
__device__ inline float dot4(float4 a, float4 b){
  return fmaf(a.x,b.x, fmaf(a.y,b.y, fmaf(a.z,b.z, a.w*b.w)));
}
// LDS-only barrier: drain LDS ops, leave global loads in flight
__device__ inline void barrier_lds(){
  __builtin_amdgcn_sched_barrier(0);
  asm volatile("s_waitcnt lgkmcnt(0)" ::: "memory");
  __builtin_amdgcn_s_barrier();
  __builtin_amdgcn_sched_barrier(0);
}

// ---------------- K0: moments + pe rank-3 decomposition tables ----------------
__global__ __launch_bounds__(256) void k0_pre(
    const float* __restrict__ pe_w, const float* __restrict__ pe_b,
    const float* __restrict__ ln_g, const float* __restrict__ ln_b,
    const float* __restrict__ pos_bias,
    float* __restrict__ pemid, float* __restrict__ alpha, float* __restrict__ beta,
    float* __restrict__ Av, float* __restrict__ Bv, float* __restrict__ Cv,
    float* __restrict__ pbT) {
  __shared__ float red[5][256];
  const int t = threadIdx.x;
  float sw=0.f, sb=0.f, sww=0.f, swb=0.f, sbb=0.f;
  for (int j=t; j<HDIM; j+=256) {
    float w=pe_w[j], b=pe_b[j];
    sw+=w; sb+=b; sww+=w*w; swb+=w*b; sbb+=b*b;
  }
  red[0][t]=sw; red[1][t]=sb; red[2][t]=sww; red[3][t]=swb; red[4][t]=sbb;
  __syncthreads();
  for (int off=128; off>0; off>>=1) {
    if (t<off) {
      red[0][t]+=red[0][t+off]; red[1][t]+=red[1][t+off]; red[2][t]+=red[2][t+off];
      red[3][t]+=red[3][t+off]; red[4][t]+=red[4][t+off];
    }
    __syncthreads();
  }
  const float inv = 1.0f/(float)HDIM;
  const float mw=red[0][0]*inv, mc=red[1][0]*inv;
  const float Vw =red[2][0]*inv - mw*mw;
  const float Cwc=red[3][0]*inv - mw*mc;
  const float Vc =red[4][0]*inv - mc*mc;
  for (int s=t; s<288; s+=256) {
    if (s < SEQ) {
      float pos = (float)(s - MIDP) / ((float)MIDP + 1e-6f);
      float var = pos*pos*Vw + 2.f*pos*Cwc + Vc;
      float rstd = rsqrtf(var + 1e-5f);
      alpha[s] = pos*rstd; beta[s] = rstd;
    } else { alpha[s] = 0.f; beta[s] = 0.f; }
  }
  const float rstd0 = rsqrtf(Vc + 1e-5f);
  for (int j=t; j<HDIM; j+=256) {
    float g = ln_g[j];
    Av[j] = (pe_w[j]-mw)*g;
    Bv[j] = (pe_b[j]-mc)*g;
    Cv[j] = ln_b[j];
    pemid[j] = (pe_b[j]-mc)*rstd0*g + ln_b[j];
  }
  for (int i=t; i<288*16; i+=256) {
    int s = i>>4, h = i&15;
    pbT[i] = (s<SEQ && h<NH) ? pos_bias[h*SEQ+s] : 0.f;
  }
}

// ---------------- bf16-MFMA tiled GEMM, 64x64 tile, K-step 32 ----------------
__global__ __launch_bounds__(256) void gemm64_bf(
    const float* __restrict__ A, long lda, long aoffz,
    const float* __restrict__ Bm, long ldb, long boffz, int bT,
    float* __restrict__ C, long ldc, long coffz,
    int K,
    const float* __restrict__ bias, long biasoffz,
    const float* __restrict__ avec, float scale) {
  __shared__ __align__(16) unsigned short Asb[64*40];   // 5120 B
  __shared__ __align__(16) unsigned short Bsb[64*40];   // 5120 B
  const int t   = threadIdx.x;
  const int l15 = t & 15;
  const int lg  = (t >> 4) & 3;
  const int w   = t >> 6;
  const int z   = blockIdx.z;
  const long n0 = (long)blockIdx.y * 64;
  A  += (long)blockIdx.x*64*lda + (long)z*aoffz;
  Bm += (long)z*boffz;
  C  += (long)blockIdx.x*64*ldc + n0 + (long)z*coffz;

  const int srow = t >> 2;         // staging row 0..63
  const int skk  = (t & 3) * 8;    // k sub-block 0/8/16/24
  const int kB   = t >> 3;         // bT=0: k 0..31
  const int nB   = (t & 7) * 8;    // bT=0: n base

  f32x4 acc[4];
  #pragma unroll
  for (int i=0;i<4;i++){ f32x4 zz={0.f,0.f,0.f,0.f}; acc[i]=zz; }

  for (int k0 = 0; k0 < K; k0 += 32) {
    // ---- stage A (+avec) ----
    {
      const float* p = &A[(long)srow*lda + k0 + skk];
      float4 a0 = *(const float4*)p, a1 = *(const float4*)(p+4);
      if (avec) {
        float4 v0 = *(const float4*)&avec[k0+skk], v1 = *(const float4*)&avec[k0+skk+4];
        a0.x+=v0.x; a0.y+=v0.y; a0.z+=v0.z; a0.w+=v0.w;
        a1.x+=v1.x; a1.y+=v1.y; a1.z+=v1.z; a1.w+=v1.w;
      }
      uint4 pk; pk.x=cvt2(a0.x,a0.y); pk.y=cvt2(a0.z,a0.w);
      pk.z=cvt2(a1.x,a1.y); pk.w=cvt2(a1.z,a1.w);
      *(uint4*)&Asb[srow*40 + (skk ^ ((srow&3)<<3))] = pk;
    }
    // ---- stage B ----
    if (bT) {
      const float* p = &Bm[(long)(n0+srow)*ldb + k0 + skk];
      float4 b0 = *(const float4*)p, b1 = *(const float4*)(p+4);
      uint4 pk; pk.x=cvt2(b0.x,b0.y); pk.y=cvt2(b0.z,b0.w);
      pk.z=cvt2(b1.x,b1.y); pk.w=cvt2(b1.z,b1.w);
      *(uint4*)&Bsb[srow*40 + (skk ^ ((srow&3)<<3))] = pk;
    } else {
      const float* p = &Bm[(long)(k0+kB)*ldb + n0 + nB];
      float4 b0 = *(const float4*)p, b1 = *(const float4*)(p+4);
      const float bv[8] = {b0.x,b0.y,b0.z,b0.w,b1.x,b1.y,b1.z,b1.w};
      #pragma unroll
      for (int i=0;i<8;i++) {
        const int n = nB + i;
        Bsb[n*40 + (kB ^ ((n&3)<<3))] = f2bf(bv[i]);
      }
    }
    __syncthreads();
    // ---- MFMA: wave w -> output rows [w*16, w*16+16), 4 col-tiles ----
    union { uint4 q; short8 s8; } af;
    const int arow = w*16 + l15;
    af.q = *(const uint4*)&Asb[arow*40 + ((lg*8) ^ ((arow&3)<<3))];
    #pragma unroll
    for (int nt=0; nt<4; ++nt) {
      union { uint4 q; short8 s8; } bf_;
      const int brow = nt*16 + l15;
      bf_.q = *(const uint4*)&Bsb[brow*40 + ((lg*8) ^ ((brow&3)<<3))];
      acc[nt] = __builtin_amdgcn_mfma_f32_16x16x32_bf16(af.s8, bf_.s8, acc[nt], 0, 0, 0);
    }
    __syncthreads();
  }
  // ---- epilogue: C[row=w*16+lg*4+r][col=n0+nt*16+l15] ----
  #pragma unroll
  for (int nt=0; nt<4; ++nt) {
    const int col = nt*16 + l15;
    const float bsv = bias ? bias[(long)z*biasoffz + n0 + col] : 0.f;
    #pragma unroll
    for (int r=0; r<4; ++r)
      C[(long)(w*16 + lg*4 + r)*ldc + col] = (acc[nt][r] + bsv)*scale;
  }
}

// ---------------- kp: per-(b,h) scalars ca=u'.A, cb=u'.B, cc=u'.C + q'.bk ----------------
__global__ __launch_bounds__(256) void kp(
    const float* __restrict__ q, const float* __restrict__ u, const float* __restrict__ bk,
    const float* __restrict__ Av, const float* __restrict__ Bv, const float* __restrict__ Cv,
    float* __restrict__ ca, float* __restrict__ cb, float* __restrict__ cc, int nb) {
  const int wid = blockIdx.x*4 + (threadIdx.x >> 6);
  const int lane = threadIdx.x & 63;
  if (wid >= nb*NH) return;
  const int b = wid / NH, h = wid % NH;
  const float* up = u + (long)b*(NH*HDIM) + h*HDIM;
  float pa=0.f, pb_=0.f, pc=0.f;
  #pragma unroll
  for (int e=0;e<3;e++) {
    int c4 = (lane + 64*e)*4;
    float4 uu = *(const float4*)&up[c4];
    pa += dot4(uu, *(const float4*)&Av[c4]);
    pb_+= dot4(uu, *(const float4*)&Bv[c4]);
    pc += dot4(uu, *(const float4*)&Cv[c4]);
  }
  if (lane < 16) {
    float4 qq = *(const float4*)&q[(long)b*HDIM + h*HD + lane*4];
    float4 bb = *(const float4*)&bk[h*HD + lane*4];
    pc += dot4(qq, bb);
  }
  #pragma unroll
  for (int mlog=0; mlog<6; mlog++) {
    int msk = 1<<mlog;
    pa += __shfl_xor(pa, msk);
    pb_+= __shfl_xor(pb_, msk);
    pc += __shfl_xor(pc, msk);
  }
  if (lane == 0) { ca[wid]=pa; cb[wid]=pb_; cc[wid]=pc; }
}

// ---------------- K3 v8e: R17 structure + depth-2 register prefetch ----------------
// Identical numerics to R17 (2 lgkm barriers/chunk, redundant per-wave exp, padded
// colT). NEW: two 12-float4 buffers gA/gB; at top of chunk c, loads for c+2 are
// issued into the buffer freed when chunk c's data was staged (during c-1). Stage of
// c+1 uses data issued at top of c-1 -> in-flight ~1.5 chunk walls -> vmcnt stall at
// the staging point vanishes; HBM duty rises. All buffer indices compile-time.
__global__ __launch_bounds__(256, 2) void k3_v8(
    const float* __restrict__ hs, int b0,
    const float* __restrict__ u,
    const float* __restrict__ ca, const float* __restrict__ cb, const float* __restrict__ cc,
    const float* __restrict__ alpha, const float* __restrict__ beta,
    const float* __restrict__ Av, const float* __restrict__ Bv, const float* __restrict__ Cv,
    const float* __restrict__ pbT, float* __restrict__ mout) {
  const int t   = threadIdx.x;
  const int l   = t & 63;
  const int w   = t >> 6;
  const int l15 = l & 15;
  const int lg  = l >> 4;
  const int bb  = blockIdx.x;
  const int b   = b0 + bb;

  __shared__ __align__(16) unsigned short xbuf[12288 + 768*CTP]; // xrow | padded colT
  unsigned short* xrow = xbuf;
  unsigned short* colT = xbuf + 12288;
  __shared__ float sred[4][16][17];                       // 4.4 KB
  __shared__ float al_s[288], be_s[288];                  // 2.3 KB
  __shared__ float hsum[3][16];

  for (int i=t; i<288; i+=256) { al_s[i]=alpha[i]; be_s[i]=beta[i]; }

  // u' B-frags (score), wave w covers K-quarter [w*192, +192)
  const float* ub = u + (long)bb*(NH*HDIM);
  short8 uf[6];
  #pragma unroll
  for (int kt=0; kt<6; kt++) {
    union { uint4 q; short8 s8; } s; s.q = make_uint4(0,0,0,0);
    if (l15 < NH) {
      const float* p = ub + l15*HDIM + w*192 + kt*32 + lg*8;
      float4 x0 = *(const float4*)p;
      float4 x1 = *(const float4*)(p+4);
      s.q.x = cvt2(x0.x,x0.y); s.q.y = cvt2(x0.z,x0.w);
      s.q.z = cvt2(x1.x,x1.y); s.q.w = cvt2(x1.z,x1.w);
    }
    uf[kt] = s.s8;
  }
  // per-(b,h) affine scalars: needed by ALL waves (redundant exp)
  float cah=0.f, cbh=0.f, cch=0.f;
  if (l15 < NH) { cah=ca[bb*NH+l15]; cbh=cb[bb*NH+l15]; cch=cc[bb*NH+l15]; }

  f32x4 pv[12];
  #pragma unroll
  for (int i=0;i<12;i++){ f32x4 z={0.f,0.f,0.f,0.f}; pv[i]=z; }
  float rs_p=0.f, sa_p=0.f, sb_p=0.f;     // accumulated on wave 0 (lg<2) only

  const float* hrow = hs + (long)b*SEQ*HDIM;
  const int rp = t >> 5;          // 0..7: rows rp*2, rp*2+1
  const int cq = t & 31;          // interleaved col-quads: j = cq*4 + e*128 + d
  union GU { float4 v4[12]; float f[48]; };
  GU gA, gB;

#define LOAD_INTO(G, CI)                                                          \
  do {                                                                            \
    _Pragma("unroll")                                                             \
    for (int rr_=0; rr_<2; ++rr_) {                                               \
      int sg_ = (CI)*16 + rp*2 + rr_; if (sg_ > SEQ-1) sg_ = SEQ-1;               \
      _Pragma("unroll")                                                           \
      for (int e_=0; e_<6; ++e_)                                                  \
        G.v4[rr_*6+e_] = *(const float4*)&hrow[(long)sg_*HDIM + cq*4 + e_*128];   \
    }                                                                             \
  } while(0)

#define STAGE_XROW(G)                                                             \
  do {                                                                            \
    _Pragma("unroll")                                                             \
    for (int rr_=0; rr_<2; ++rr_) {                                               \
      const int srow_ = rp*2+rr_;                                                 \
      _Pragma("unroll")                                                           \
      for (int e_=0; e_<6; ++e_) {                                                \
        float4 v_ = G.v4[rr_*6+e_];                                               \
        uint2 pk_; pk_.x = cvt2(v_.x,v_.y); pk_.y = cvt2(v_.z,v_.w);              \
        const int c_ = cq*4 + e_*128;                                             \
        *(uint2*)&xrow[srow_*768 + (c_ ^ ((srow_&7)<<3))] = pk_;                  \
      }                                                                           \
    }                                                                             \
  } while(0)

#define STAGE_COLT(G)                                                             \
  do {                                                                            \
    _Pragma("unroll")                                                             \
    for (int e_=0; e_<6; ++e_)                                                    \
      _Pragma("unroll")                                                           \
      for (int d_=0; d_<4; ++d_) {                                                \
        const int j_ = cq*4 + e_*128 + d_;                                        \
        unsigned v_ = cvt2(G.f[e_*4+d_], G.f[24+e_*4+d_]);                        \
        *(unsigned*)&colT[j_*CTP + rp*2] = v_;                                    \
      }                                                                           \
  } while(0)

// one chunk: compute chunk CI (in LDS); issue loads CI+2 into GLD; stage CI+1 from GST
#define CHUNK_BODY(CI, GLD, GST, DOLOAD, DOSTAGE)                                 \
  do {                                                                            \
    const int ci_ = (CI);                                                         \
    float pb_r[8];                                                                \
    if (lg < 2) {                                                                 \
      _Pragma("unroll")                                                           \
      for (int e_=0; e_<8; ++e_)                                                  \
        pb_r[e_] = pbT[(ci_*16 + lg*8 + e_)*16 + l15];                            \
    }                                                                             \
    if (DOLOAD) LOAD_INTO(GLD, ci_+2);                                            \
    {                                                                             \
      f32x4 acc = {0.f,0.f,0.f,0.f};                                              \
      _Pragma("unroll")                                                           \
      for (int kt_=0; kt_<6; kt_++) {                                             \
        const int col_ = w*192 + kt_*32 + lg*8;                                   \
        uint4 raw_ = *(const uint4*)&xrow[l15*768 + (col_ ^ ((l15&7)<<3))];       \
        union { uint4 q; short8 s8; } A_; A_.q = raw_;                            \
        acc = __builtin_amdgcn_mfma_f32_16x16x32_bf16(A_.s8, uf[kt_], acc, 0,0,0);\
      }                                                                           \
      _Pragma("unroll")                                                           \
      for (int r_=0; r_<4; ++r_) sred[w][lg*4+r_][l15] = acc[r_];                 \
    }                                                                             \
    barrier_lds();                       /* BAR1: sred ready, xrow free */        \
    union { uint4 q; short8 s8; } B_; B_.q = make_uint4(0,0,0,0);                 \
    if (lg < 2) {                                                                 \
      _Pragma("unroll")                                                           \
      for (int e_=0; e_<8; ++e_) {                                                \
        const int s_ = lg*8 + e_, sg_ = ci_*16 + s_;                              \
        float S_ = sred[0][s_][l15]+sred[1][s_][l15]+sred[2][s_][l15]+sred[3][s_][l15];\
        float al_ = al_s[sg_], be_ = be_s[sg_];                                   \
        float sc_ = S_ + fmaf(cah, al_, fmaf(cbh, be_, cch)) + pb_r[e_];          \
        float wv_ = (sg_ < SEQ && l15 < NH) ? __expf(sc_) : 0.f;                  \
        unsigned short wb_ = f2bf(wv_);                                           \
        B_.s8[e_] = (short)wb_;                                                   \
        if (w == 0) {                                                             \
          float wr_ = bf2f(wb_);                                                  \
          rs_p += wr_; sa_p = fmaf(wr_, al_, sa_p); sb_p = fmaf(wr_, be_, sb_p);  \
        }                                                                         \
      }                                                                           \
    }                                                                             \
    {                                                                             \
      _Pragma("unroll")                                                           \
      for (int tau_=0; tau_<12; ++tau_) {                                         \
        const int j_ = w*192 + tau_*16 + l15;                                     \
        union { uint4 q; short8 s8; } A_; A_.q = make_uint4(0,0,0,0);             \
        if (lg < 2) A_.q = *(const uint4*)&colT[j_*CTP + lg*8];                   \
        pv[tau_] = __builtin_amdgcn_mfma_f32_16x16x32_bf16(A_.s8, B_.s8, pv[tau_], 0,0,0);\
      }                                                                           \
      if (DOSTAGE) STAGE_XROW(GST);      /* xrow(ci+1); data issued at ci-1 */    \
    }                                                                             \
    barrier_lds();                       /* BAR2: PV done, xrow(ci+1) drained */  \
    if (DOSTAGE) STAGE_COLT(GST);        /* drains at BAR1(ci+1) */               \
  } while(0)

  // ---- prologue: chunk0 -> gA, chunk1 -> gB; stage chunk0 from gA ----
  LOAD_INTO(gA, 0);
  LOAD_INTO(gB, 1);
  STAGE_XROW(gA);
  STAGE_COLT(gA);
  __syncthreads();

  // 17 chunks: pairs (0,1)..(14,15), tail 16.
  #pragma unroll 1
  for (int cc = 0; cc < 16; cc += 2) {
    CHUNK_BODY(cc,   gA, gB, (cc+2 <= 16), true);
    CHUNK_BODY(cc+1, gB, gA, (cc+3 <= 16), true);
  }
  CHUNK_BODY(16, gA, gB, false, false);

#undef CHUNK_BODY
#undef STAGE_COLT
#undef STAGE_XROW
#undef LOAD_INTO

  // ---- softmax sums (wave 0, lg<2 lanes hold partials; xor over lg sums them) ----
  if (w == 0) {
    rs_p += __shfl_xor(rs_p,16); rs_p += __shfl_xor(rs_p,32);
    sa_p += __shfl_xor(sa_p,16); sa_p += __shfl_xor(sa_p,32);
    sb_p += __shfl_xor(sb_p,16); sb_p += __shfl_xor(sb_p,32);
    if (l < 16) { hsum[0][l15]=rs_p; hsum[1][l15]=sa_p; hsum[2][l15]=sb_p; }
  }
  __syncthreads();

  // ---- m^T regs -> LDS (overlay xbuf), then coalesced epilogue ----
  float* mlds = (float*)xbuf;             // [12][772]
  if (l15 < NH) {
    #pragma unroll
    for (int tau=0; tau<12; ++tau)
      #pragma unroll
      for (int r=0; r<4; ++r) {
        const int j = w*192 + tau*16 + lg*4 + r;
        mlds[l15*772 + j] = pv[tau][r];
      }
  }
  __syncthreads();
  float* mo = mout + (long)bb*(NH*HDIM);
  #pragma unroll
  for (int e=0; e<9; ++e) {
    const int idx = t + 256*e;            // 0..2303
    const int h = idx/192, c4 = (idx%192)*4;
    const float invr = 1.0f/hsum[0][h];
    const float fa = hsum[1][h]*invr, fb = hsum[2][h]*invr;
    float4 mv = *(const float4*)&mlds[h*772 + c4];
    float4 av = *(const float4*)&Av[c4];
    float4 bv4 = *(const float4*)&Bv[c4];
    float4 cv4 = *(const float4*)&Cv[c4];
    float4 o;
    o.x = fmaf(mv.x, invr, fmaf(fa, av.x, fmaf(fb, bv4.x, cv4.x)));
    o.y = fmaf(mv.y, invr, fmaf(fa, av.y, fmaf(fb, bv4.y, cv4.y)));
    o.z = fmaf(mv.z, invr, fmaf(fa, av.z, fmaf(fb, bv4.z, cv4.z)));
    o.w = fmaf(mv.w, invr, fmaf(fa, av.w, fmaf(fb, bv4.w, cv4.w)));
    *(float4*)&mo[h*HDIM + c4] = o;
  }
}

extern "C" void kernel_launch(void* const* d_in, const int* in_sizes, int n_in,
                              void* d_out, int out_size, void* d_ws, size_t ws_size,
                              hipStream_t stream) {
  (void)in_sizes; (void)n_in; (void)out_size;
  const float* hs   = (const float*)d_in[0];
  const float* Wq   = (const float*)d_in[1];
  const float* bq   = (const float*)d_in[2];
  const float* Wk   = (const float*)d_in[3];
  const float* bk   = (const float*)d_in[4];
  const float* Wv   = (const float*)d_in[5];
  const float* bv   = (const float*)d_in[6];
  const float* Wo   = (const float*)d_in[7];
  const float* bo   = (const float*)d_in[8];
  const float* pe_w = (const float*)d_in[9];
  const float* pe_b = (const float*)d_in[10];
  const float* ln_g = (const float*)d_in[11];
  const float* ln_b = (const float*)d_in[12];
  const float* pos_bias = (const float*)d_in[13];
  float* out = (float*)d_out;

  float* wsf   = (float*)d_ws;
  float* pemid = wsf;               // 768
  float* alpha = pemid + 768;       // 288
  float* beta  = alpha + 288;       // 288
  float* Avec  = beta  + 288;       // 768
  float* Bvec  = Avec  + 768;       // 768
  float* Cvec  = Bvec  + 768;       // 768
  float* pbT   = Cvec  + 768;       // 288*16 = 4608
  float* base  = pbT   + 4608;      // fixed total = 8256 floats

  const long perB = 768L + 36L + 9216L + 9216L + 768L;   // q + (ca,cb,cc) + u + m + ctx
  long availF = (long)(ws_size/4) - 8256;
  long chunkB = (availF > 0) ? (availF / perB) : 0;
  if (chunkB > BTOT) chunkB = BTOT;
  chunkB &= ~63L;
  if (chunkB < 64) chunkB = 64;

  float* qb   = base;
  float* cab  = qb  + chunkB*HDIM;
  float* cbb  = cab + chunkB*NH;
  float* ccb  = cbb + chunkB*NH;
  float* ub   = ccb + chunkB*NH;
  float* mb   = ub  + chunkB*(long)NH*HDIM;
  float* ctxb = mb  + chunkB*(long)NH*HDIM;

  k0_pre<<<dim3(1), dim3(256), 0, stream>>>(pe_w, pe_b, ln_g, ln_b, pos_bias,
                                            pemid, alpha, beta, Avec, Bvec, Cvec, pbT);

  for (long b0 = 0; b0 < BTOT; b0 += chunkB) {
    long cbN = (BTOT - b0 < chunkB) ? (BTOT - b0) : chunkB;
    int mt = (int)(cbN/64);
    // K1: q' = 0.125*((hs[:,mid,:] + pe_mid) @ Wq^T + bq)
    gemm64_bf<<<dim3(mt,12,1), dim3(256), 0, stream>>>(
        hs + b0*(long)SEQ*HDIM + (long)MIDP*HDIM, (long)SEQ*HDIM, 0L,
        Wq, (long)HDIM, 0L, 1,
        qb, (long)HDIM, 0L,
        HDIM, bq, 0L, pemid, 0.125f);
    // K2: u'[b,h,:] = q'[b,h,:] @ Wk_h
    gemm64_bf<<<dim3(mt,12,12), dim3(256), 0, stream>>>(
        qb, (long)HDIM, (long)HD,
        Wk, (long)HDIM, (long)HD*HDIM, 0,
        ub, (long)NH*HDIM, (long)HDIM,
        HD, (const float*)nullptr, 0L, (const float*)nullptr, 1.0f);
    // kp: per-(b,h) pe/bias dot scalars
    int nw = (int)(cbN*NH);
    kp<<<dim3((nw+3)/4), dim3(256), 0, stream>>>(qb, ub, bk, Avec, Bvec, Cvec,
                                                 cab, cbb, ccb, (int)cbN);
    // K3: fused MFMA scores + softmax-weighted mean
    k3_v8<<<dim3((int)cbN), dim3(256), 0, stream>>>(
        hs, (int)b0, ub, cab, cbb, ccb, alpha, beta, Avec, Bvec, Cvec, pbT, mb);
    // K4: ctx = Wv_h @ m + bv
    gemm64_bf<<<dim3(mt,1,12), dim3(256), 0, stream>>>(
        mb, (long)NH*HDIM, (long)HDIM,
        Wv, (long)HDIM, (long)HD*HDIM, 1,
        ctxb, (long)HDIM, (long)HD,
        HDIM, bv, (long)HD, (const float*)nullptr, 1.0f);
    // K5: out = ctx @ Wo^T + bo
    gemm64_bf<<<dim3(mt,12,1), dim3(256), 0, stream>>>(
        ctxb, (long)HDIM, 0L,
        Wo, (long)HDIM, 0L, 1,
        out + b0*(long)HDIM, (long)HDIM, 0L,
        HDIM, bo, 0L, (const float*)nullptr, 1.0f);
  }
}